// Round 13
// baseline (785.253 us; speedup 1.0000x reference)
//
#include <hip/hip_runtime.h>
#include <cstdint>

#define H 1024
#define F 2048
#define E_N 8
#define BM 256
#define BK 64
#define NW (E_N * F * H)

typedef __attribute__((ext_vector_type(8))) short short8v;
typedef __attribute__((ext_vector_type(4))) float float4v;
typedef unsigned short u16;

__device__ __forceinline__ u16 f2bf(float f) {
    uint32_t u = __float_as_uint(f);
    u += 0x7FFFu + ((u >> 16) & 1u);   // round-to-nearest-even
    return (u16)(u >> 16);
}
__device__ __forceinline__ float bf2f(u16 b) {
    return __uint_as_float(((uint32_t)b) << 16);
}

__device__ __forceinline__ void gload16(const void* g, void* l) {
    __builtin_amdgcn_global_load_lds((const __attribute__((address_space(1))) uint32_t*)g,
                                     (__attribute__((address_space(3))) uint32_t*)l, 16, 0, 0);
}

// raw barrier (no vmcnt drain) with compiler memory fence
__device__ __forceinline__ void barx() {
    asm volatile("" ::: "memory");
    __builtin_amdgcn_s_barrier();
    asm volatile("" ::: "memory");
}

// bijective XCD chunk swizzle (m204) + tile-mid / gy-inner order
__device__ __forceinline__ void decode_swz(int bid, int nTiles, int ngy, int gyc,
                                           int& tile, int& gy) {
    int nblk = nTiles * ngy;
    int q = nblk >> 3, r = nblk & 7;
    int xcd = bid & 7, pos = bid >> 3;
    int cid = (xcd < r ? xcd * (q + 1) : r * (q + 1) + (xcd - r) * q) + pos;
    int per = nTiles * gyc;
    int chunk = cid / per, rem = cid - chunk * per;
    tile = rem / gyc;
    gy = chunk * gyc + (rem - (rem / gyc) * gyc);
}

// ---------------- fp32 -> bf16, 3 weight tensors in one launch ----------------
__global__ __launch_bounds__(256) void cvt3_kernel(const float* __restrict__ s0,
                                                   const float* __restrict__ s1,
                                                   const float* __restrict__ s2,
                                                   u16* __restrict__ dst) {
    int i = (blockIdx.x * 256 + threadIdx.x) * 4;
    int stride = gridDim.x * 256 * 4;
    for (; i < 3 * NW; i += stride) {
        int seg = i / NW;
        int off = i - seg * NW;
        const float* s = (seg == 0) ? s0 : ((seg == 1) ? s1 : s2);
        float4 v = *(const float4*)(s + off);
        ushort4 o;
        o.x = f2bf(v.x); o.y = f2bf(v.y); o.z = f2bf(v.z); o.w = f2bf(v.w);
        *(ushort4*)(dst + i) = o;
    }
}

// ---------------- router (no atomics) + fused x->bf16 ----------------
__global__ __launch_bounds__(256) void router_kernel(const float* __restrict__ x,
                                                     const float* __restrict__ gw,
                                                     int* __restrict__ topi,
                                                     float* __restrict__ topw,
                                                     u16* __restrict__ xg, int T) {
    int wave = threadIdx.x >> 6, lane = threadIdx.x & 63;
    int t = blockIdx.x * 4 + wave;
    if (t >= T) return;
    const float4* xr = (const float4*)(x + (size_t)t * H);
    float4 xv[4];
#pragma unroll
    for (int i = 0; i < 4; i++) xv[i] = xr[i * 64 + lane];
#pragma unroll
    for (int i = 0; i < 4; i++) {
        ushort4 o;
        o.x = f2bf(xv[i].x); o.y = f2bf(xv[i].y);
        o.z = f2bf(xv[i].z); o.w = f2bf(xv[i].w);
        *(ushort4*)(xg + (size_t)t * H + (i * 64 + lane) * 4) = o;
    }
    float acc[E_N];
#pragma unroll
    for (int e = 0; e < E_N; e++) {
        const float4* gr = (const float4*)(gw + e * H);
        float s = 0.f;
#pragma unroll
        for (int i = 0; i < 4; i++) {
            float4 g = gr[i * 64 + lane];
            s += xv[i].x * g.x + xv[i].y * g.y + xv[i].z * g.z + xv[i].w * g.w;
        }
        acc[e] = s;
    }
#pragma unroll
    for (int e = 0; e < E_N; e++) {
#pragma unroll
        for (int off = 32; off; off >>= 1) acc[e] += __shfl_xor(acc[e], off, 64);
    }
    if (lane == 0) {
        int i0 = 0;
#pragma unroll
        for (int e = 1; e < E_N; e++) if (acc[e] > acc[i0]) i0 = e;
        int i1 = -1;
#pragma unroll
        for (int e = 0; e < E_N; e++) {
            if (e == i0) continue;
            if (i1 < 0 || acc[e] > acc[i1]) i1 = e;
        }
        float e1 = __expf(acc[i1] - acc[i0]);
        float w0 = 1.f / (1.f + e1);
        float w1v = e1 / (1.f + e1);
        topi[t * 2] = i0; topi[t * 2 + 1] = i1;
        topw[t * 2] = w0; topw[t * 2 + 1] = w1v;
    }
}

// ---------------- histogram: 8 global atomics per block ----------------
__global__ __launch_bounds__(256) void hist_kernel(const int* __restrict__ topi,
                                                   int* __restrict__ counts, int n) {
    __shared__ int hc[E_N];
    if (threadIdx.x < E_N) hc[threadIdx.x] = 0;
    __syncthreads();
    for (int i = blockIdx.x * 256 + threadIdx.x; i < n; i += gridDim.x * 256)
        atomicAdd(&hc[topi[i]], 1);
    __syncthreads();
    if (threadIdx.x < E_N) atomicAdd(&counts[threadIdx.x], hc[threadIdx.x]);
}

// ---------------- tiny serial scan ----------------
__global__ void scan_kernel(const int* __restrict__ counts, int* __restrict__ offsets,
                            int* __restrict__ cursors, int* __restrict__ tileOff) {
    if (threadIdx.x == 0 && blockIdx.x == 0) {
        int o = 0, to = 0;
        for (int e = 0; e < E_N; e++) {
            offsets[e] = o; cursors[e] = o; tileOff[e] = to;
            o += counts[e];
            to += (counts[e] + BM - 1) / BM;
        }
        offsets[E_N] = o; tileOff[E_N] = to;
    }
}

// ---------------- scatter: block-local ranks, 8 global atomics per block ----------------
__global__ __launch_bounds__(1024) void scatter_kernel(const int* __restrict__ topi,
                                                       const float* __restrict__ topw,
                                                       int* __restrict__ cursors,
                                                       int* __restrict__ perm_tok,
                                                       float* __restrict__ perm_gate,
                                                       int* __restrict__ inv, int n) {
    __shared__ int hc[E_N];
    __shared__ int base[E_N];
    int tid = threadIdx.x;
    if (tid < E_N) hc[tid] = 0;
    __syncthreads();
    int i = blockIdx.x * 1024 + tid;
    int e = 0, lrank = 0;
    bool ok = (i < n);
    if (ok) {
        e = topi[i];
        lrank = atomicAdd(&hc[e], 1);
    }
    __syncthreads();
    if (tid < E_N) base[tid] = atomicAdd(&cursors[tid], hc[tid]);
    __syncthreads();
    if (ok) {
        int pos = base[e] + lrank;
        perm_tok[pos] = i >> 1;
        perm_gate[pos] = topw[i];
        inv[i] = pos;
    }
}

// ---------------- stage 1: h = gate * silu(xg@w1^T) * (xg@w3^T) ----------------
// 256-row tile, BN=128 (dual w1/w3), 8 waves. A staged in LDS (dbuf 64 KB ->
// 2 blocks/CU); B loaded DIRECTLY into registers (dbuf, issued 1 K-tile ahead).
// 2 barriers per K-tile. Per-tile VMEM = 8 B-reg + 4 A-lds = 12:
//   mid: vmcnt(10) -> this tile's A j1,j3 (oldest 2) landed
//   end: vmcnt(2)  -> next tile's B + A j0,j2 (oldest 10) landed
__global__ __launch_bounds__(512) void stage1_kernel(
    const u16* __restrict__ xg, const u16* __restrict__ w1b, const u16* __restrict__ w3b,
    const int* __restrict__ perm_tok, const float* __restrict__ perm_gate,
    const int* __restrict__ offsets, const int* __restrict__ tileOff,
    u16* __restrict__ h, int cstart, int tpcThis) {
    __shared__ u16 lA[2 * BM * BK];      // 64 KB, buf stride 16384 elems
    __shared__ int ptokS[BM];
    __shared__ float pgateS[BM];

    int tileL, nbIdx;
    decode_swz(blockIdx.x, tpcThis, F / 128, 4, tileL, nbIdx);
    int tile = cstart + tileL;
    if (tile >= tileOff[E_N]) return;
    int e = 0;
    while (e < E_N - 1 && tile >= tileOff[e + 1]) e++;
    int rbase = offsets[e] + (tile - tileOff[e]) * BM;
    int segEnd = offsets[e + 1];
    int e0 = 0;
    while (e0 < E_N - 1 && cstart >= tileOff[e0 + 1]) e0++;
    int chunkBase = offsets[e0] + (cstart - tileOff[e0]) * BM;

    int tid = threadIdx.x;
    if (tid < BM) {
        int p = rbase + tid; if (p > segEnd - 1) p = segEnd - 1;
        ptokS[tid] = perm_tok[p];
        pgateS[tid] = perm_gate[p];
    }
    __syncthreads();

    int lane = tid & 63, wid = tid >> 6;
    int wr = wid >> 2, wc = wid & 3;
    int lrow = lane & 15, kgrp = lane >> 4;
    int lr = lane >> 3, csw = ((lane & 7) ^ lr) << 3;
    int nb = nbIdx * 128;
    const u16* w1p = w1b + (size_t)e * F * H + (size_t)nb * H;
    const u16* w3p = w3b + (size_t)e * F * H + (size_t)nb * H;

    // A staging pointers (swizzled-source; advance +BK per K-tile)
    const u16* pA[4];
#pragma unroll
    for (int j = 0; j < 4; j++) pA[j] = xg + (size_t)ptokS[(j * 8 + wid) * 8 + lr] * H + csw;

    // B direct-load pointers: logical element (row = wc*32+n*16+lrow, k = kgrp*8 + kk*32)
    const u16 *pB1g[2], *pB3g[2];
#pragma unroll
    for (int n = 0; n < 2; n++) {
        int bcol = wc * 32 + n * 16 + lrow;
        pB1g[n] = w1p + (size_t)bcol * H + kgrp * 8;
        pB3g[n] = w3p + (size_t)bcol * H + kgrp * 8;
    }

    // hoisted A ds_read element bases (r&7 == lrow&7 for all fragment rows)
    int swe0 = (kgrp ^ (lrow & 7)) << 3;
    int swe1 = ((4 + kgrp) ^ (lrow & 7)) << 3;
    int eA0 = (wr * 128 + lrow) * BK + swe0;
    int eA1 = (wr * 128 + lrow) * BK + swe1;

#define STA(CC, j)  gload16(pA[j],  &lA[(CC) * 16384 + ((j) * 8 + wid) * 8 * BK])
#define LDB1(CC) \
    _Pragma("unroll") \
    for (int n = 0; n < 2; n++) { \
        b1R[CC][n][0] = *(const short8v*)(pB1g[n]); \
        b1R[CC][n][1] = *(const short8v*)(pB1g[n] + 32); \
    }
#define LDB3(CC) \
    _Pragma("unroll") \
    for (int n = 0; n < 2; n++) { \
        b3R[CC][n][0] = *(const short8v*)(pB3g[n]); \
        b3R[CC][n][1] = *(const short8v*)(pB3g[n] + 32); \
    }

    short8v b1R[2][2][2], b3R[2][2][2];   // [buf][n][kk], all indices literal
    float4v acc1[8][2], acc3[8][2];
#pragma unroll
    for (int a = 0; a < 8; a++)
#pragma unroll
        for (int b = 0; b < 2; b++) { acc1[a][b] = (float4v)(0.f); acc3[a][b] = (float4v)(0.f); }

    // prologue: B(t0) regs first, then A j0,j2,j1,j3 -> vmcnt(2) leaves j1,j3 in flight
    LDB1(0) LDB3(0)
    STA(0, 0); STA(0, 2); STA(0, 1); STA(0, 3);
#pragma unroll
    for (int j = 0; j < 4; j++) pA[j] += BK;
    pB1g[0] += BK; pB1g[1] += BK; pB3g[0] += BK; pB3g[1] += BK;
    asm volatile("s_waitcnt vmcnt(2)" ::: "memory");
    barx();

#define S1_DSA(CC, p) \
    short8v aF[2][2]; \
    _Pragma("unroll") \
    for (int pm = 0; pm < 2; pm++) { \
        aF[pm][0] = *(const short8v*)&lA[eA0 + (CC) * 16384 + (2 * (p) + pm) * 1024]; \
        aF[pm][1] = *(const short8v*)&lA[eA1 + (CC) * 16384 + (2 * (p) + pm) * 1024]; \
    }
#define S1_MM(CC, p) \
    __builtin_amdgcn_s_setprio(1); \
    _Pragma("unroll") \
    for (int pm = 0; pm < 2; pm++) \
    _Pragma("unroll") \
    for (int n = 0; n < 2; n++) \
    _Pragma("unroll") \
    for (int kk = 0; kk < 2; kk++) { \
        acc1[2 * (p) + pm][n] = __builtin_amdgcn_mfma_f32_16x16x32_bf16(aF[pm][kk], b1R[CC][n][kk], acc1[2 * (p) + pm][n], 0, 0, 0); \
        acc3[2 * (p) + pm][n] = __builtin_amdgcn_mfma_f32_16x16x32_bf16(aF[pm][kk], b3R[CC][n][kk], acc3[2 * (p) + pm][n], 0, 0, 0); \
    } \
    __builtin_amdgcn_s_setprio(0);

#define S1_KT(CC, LAST) { \
    { S1_DSA(CC, 0) \
      if (!(LAST)) { LDB1((CC) ^ 1) STA((CC) ^ 1, 0); } \
      S1_MM(CC, 0) } \
    { S1_DSA(CC, 1) \
      if (!(LAST)) { LDB3((CC) ^ 1) STA((CC) ^ 1, 2); } \
      S1_MM(CC, 1) } \
    if (!(LAST)) { asm volatile("s_waitcnt vmcnt(10)" ::: "memory"); } \
    else         { asm volatile("s_waitcnt vmcnt(0)" ::: "memory"); } \
    barx(); \
    { S1_DSA(CC, 2) \
      if (!(LAST)) { STA((CC) ^ 1, 1); } \
      S1_MM(CC, 2) } \
    { S1_DSA(CC, 3) \
      if (!(LAST)) { STA((CC) ^ 1, 3); } \
      S1_MM(CC, 3) } \
    if (!(LAST)) { asm volatile("s_waitcnt vmcnt(2)" ::: "memory"); } \
    else         { asm volatile("s_waitcnt vmcnt(0)" ::: "memory"); } \
    barx(); \
    _Pragma("unroll") \
    for (int j = 0; j < 4; j++) pA[j] += BK; \
    pB1g[0] += BK; pB1g[1] += BK; pB3g[0] += BK; pB3g[1] += BK; \
}

    // NT = H/BK = 16 K-tiles, unrolled x2 for compile-time buffer index
    for (int tt = 0; tt < (H / BK) - 2; tt += 2) {
        S1_KT(0, false)
        S1_KT(1, false)
    }
    S1_KT(0, false)
    S1_KT(1, true)
#undef S1_DSA
#undef S1_MM
#undef S1_KT
#undef STA
#undef LDB1
#undef LDB3

    int rif = (lane >> 4) * 4;
#pragma unroll
    for (int m = 0; m < 8; m++) {
#pragma unroll
        for (int reg = 0; reg < 4; reg++) {
            int rowIdx = wr * 128 + m * 16 + rif + reg;
            int p = rbase + rowIdx;
            if (p < segEnd) {
                float g = pgateS[rowIdx];
#pragma unroll
                for (int n = 0; n < 2; n++) {
                    float a1 = acc1[m][n][reg], a3 = acc3[m][n][reg];
                    float sv = a1 / (1.f + __expf(-a1));
                    float hv = sv * a3 * g;
                    int ncol = nb + wc * 32 + n * 16 + (lane & 15);
                    h[(size_t)(p - chunkBase) * F + ncol] = f2bf(hv);
                }
            }
        }
    }
}

// ---------------- stage 2: y[p] = h[p] @ w2^T ----------------
// 256-row tile, BN = NREP*64, 8 waves; A in LDS (dbuf 64 KB -> 2 blocks/CU),
// B (w2) direct into registers. 2 barriers per K-tile, counted vmcnt:
//   NREP=4: 12 VMEM/tile -> mid vmcnt(10), end vmcnt(2)
//   NREP=2:  8 VMEM/tile -> mid vmcnt(6),  end vmcnt(2)
template<int NREP>
__global__ __launch_bounds__(512) void stage2_kernel(
    const u16* __restrict__ h, const u16* __restrict__ w2b,
    const int* __restrict__ offsets, const int* __restrict__ tileOff,
    u16* __restrict__ y, int cstart, int tpcThis) {
    constexpr int BN = NREP * 64;
    __shared__ u16 lA[2 * BM * BK];

    int tileL, nbIdx;
    decode_swz(blockIdx.x, tpcThis, H / BN, 4, tileL, nbIdx);
    int tile = cstart + tileL;
    if (tile >= tileOff[E_N]) return;
    int e = 0;
    while (e < E_N - 1 && tile >= tileOff[e + 1]) e++;
    int rbase = offsets[e] + (tile - tileOff[e]) * BM;
    int segEnd = offsets[e + 1];
    int e0 = 0;
    while (e0 < E_N - 1 && cstart >= tileOff[e0 + 1]) e0++;
    int chunkBase = offsets[e0] + (cstart - tileOff[e0]) * BM;

    int tid = threadIdx.x;
    int lane = tid & 63, wid = tid >> 6;
    int wr = wid >> 2, wc = wid & 3;
    int lrow = lane & 15, kgrp = lane >> 4;
    int lr = lane >> 3, csw = ((lane & 7) ^ lr) << 3;
    int nb = nbIdx * BN;
    const u16* w2p = w2b + (size_t)e * H * F + (size_t)nb * F;

    const u16* pA[4];
#pragma unroll
    for (int j = 0; j < 4; j++) {
        int rb = (j * 8 + wid) * 8;
        int p = rbase + rb + lr; if (p > segEnd - 1) p = segEnd - 1;
        pA[j] = h + (size_t)(p - chunkBase) * F + csw;
    }
    const u16* pBg[NREP];
#pragma unroll
    for (int n = 0; n < NREP; n++)
        pBg[n] = w2p + (size_t)(wc * (NREP * 16) + n * 16 + lrow) * F + kgrp * 8;

    int swe0 = (kgrp ^ (lrow & 7)) << 3;
    int swe1 = ((4 + kgrp) ^ (lrow & 7)) << 3;
    int eA0 = (wr * 128 + lrow) * BK + swe0;
    int eA1 = (wr * 128 + lrow) * BK + swe1;

#define STA2(CC, j) gload16(pA[j], &lA[(CC) * 16384 + ((j) * 8 + wid) * 8 * BK])
#define LDB2A(CC) \
    _Pragma("unroll") \
    for (int n = 0; n < NREP / 2; n++) { \
        bR[CC][n][0] = *(const short8v*)(pBg[n]); \
        bR[CC][n][1] = *(const short8v*)(pBg[n] + 32); \
    }
#define LDB2B(CC) \
    _Pragma("unroll") \
    for (int n = NREP / 2; n < NREP; n++) { \
        bR[CC][n][0] = *(const short8v*)(pBg[n]); \
        bR[CC][n][1] = *(const short8v*)(pBg[n] + 32); \
    }

    short8v bR[2][NREP][2];
    float4v acc[8][NREP];
#pragma unroll
    for (int a = 0; a < 8; a++)
#pragma unroll
        for (int b = 0; b < NREP; b++) acc[a][b] = (float4v)(0.f);

    // prologue
    LDB2A(0) LDB2B(0)
    STA2(0, 0); STA2(0, 2); STA2(0, 1); STA2(0, 3);
#pragma unroll
    for (int j = 0; j < 4; j++) pA[j] += BK;
#pragma unroll
    for (int n = 0; n < NREP; n++) pBg[n] += BK;
    asm volatile("s_waitcnt vmcnt(2)" ::: "memory");
    barx();

#define S2_DSA(CC, p) \
    short8v aF[2][2]; \
    _Pragma("unroll") \
    for (int pm = 0; pm < 2; pm++) { \
        aF[pm][0] = *(const short8v*)&lA[eA0 + (CC) * 16384 + (2 * (p) + pm) * 1024]; \
        aF[pm][1] = *(const short8v*)&lA[eA1 + (CC) * 16384 + (2 * (p) + pm) * 1024]; \
    }
#define S2_MM(CC, p) \
    __builtin_amdgcn_s_setprio(1); \
    _Pragma("unroll") \
    for (int pm = 0; pm < 2; pm++) \
    _Pragma("unroll") \
    for (int n = 0; n < NREP; n++) \
    _Pragma("unroll") \
    for (int kk = 0; kk < 2; kk++) \
        acc[2 * (p) + pm][n] = __builtin_amdgcn_mfma_f32_16x16x32_bf16(aF[pm][kk], bR[CC][n][kk], acc[2 * (p) + pm][n], 0, 0, 0); \
    __builtin_amdgcn_s_setprio(0);

#define S2_KT(CC, LAST) { \
    { S2_DSA(CC, 0) \
      if (!(LAST)) { LDB2A((CC) ^ 1) STA2((CC) ^ 1, 0); } \
      S2_MM(CC, 0) } \
    { S2_DSA(CC, 1) \
      if (!(LAST)) { LDB2B((CC) ^ 1) STA2((CC) ^ 1, 2); } \
      S2_MM(CC, 1) } \
    if (!(LAST)) { \
        if (NREP == 4) { asm volatile("s_waitcnt vmcnt(10)" ::: "memory"); } \
        else           { asm volatile("s_waitcnt vmcnt(6)" ::: "memory"); } \
    } else { asm volatile("s_waitcnt vmcnt(0)" ::: "memory"); } \
    barx(); \
    { S2_DSA(CC, 2) \
      if (!(LAST)) { STA2((CC) ^ 1, 1); } \
      S2_MM(CC, 2) } \
    { S2_DSA(CC, 3) \
      if (!(LAST)) { STA2((CC) ^ 1, 3); } \
      S2_MM(CC, 3) } \
    if (!(LAST)) { asm volatile("s_waitcnt vmcnt(2)" ::: "memory"); } \
    else         { asm volatile("s_waitcnt vmcnt(0)" ::: "memory"); } \
    barx(); \
    _Pragma("unroll") \
    for (int j = 0; j < 4; j++) pA[j] += BK; \
    _Pragma("unroll") \
    for (int n = 0; n < NREP; n++) pBg[n] += BK; \
}

    for (int tt = 0; tt < (F / BK) - 2; tt += 2) {
        S2_KT(0, false)
        S2_KT(1, false)
    }
    S2_KT(0, false)
    S2_KT(1, true)
#undef S2_DSA
#undef S2_MM
#undef S2_KT
#undef STA2
#undef LDB2A
#undef LDB2B

    int rif = (lane >> 4) * 4;
#pragma unroll
    for (int m = 0; m < 8; m++) {
#pragma unroll
        for (int reg = 0; reg < 4; reg++) {
            int rowIdx = wr * 128 + m * 16 + rif + reg;
            int p = rbase + rowIdx;
            if (p < segEnd) {
#pragma unroll
                for (int n = 0; n < NREP; n++) {
                    int col = nb + wc * (BN / 4) + n * 16 + (lane & 15);
                    y[(size_t)p * H + col] = f2bf(acc[m][n][reg]);
                }
            }
        }
    }
}

// ---------------- combine: out[t] = y[slot0] + y[slot1] ----------------
__global__ __launch_bounds__(256) void combine_kernel(const u16* __restrict__ y,
                                                      const int* __restrict__ inv,
                                                      float* __restrict__ out) {
    int t = blockIdx.x, c = threadIdx.x;
    int s0 = inv[t * 2], s1 = inv[t * 2 + 1];
    ushort4 a = *(const ushort4*)(y + (size_t)s0 * H + c * 4);
    ushort4 b = *(const ushort4*)(y + (size_t)s1 * H + c * 4);
    float4 o;
    o.x = bf2f(a.x) + bf2f(b.x);
    o.y = bf2f(a.y) + bf2f(b.y);
    o.z = bf2f(a.z) + bf2f(b.z);
    o.w = bf2f(a.w) + bf2f(b.w);
    *(float4*)(out + (size_t)t * H + c * 4) = o;
}

extern "C" void kernel_launch(void* const* d_in, const int* in_sizes, int n_in,
                              void* d_out, int out_size, void* d_ws, size_t ws_size,
                              hipStream_t stream) {
    (void)n_in; (void)out_size;
    const float* x  = (const float*)d_in[0];
    const float* gw = (const float*)d_in[1];
    const float* w1 = (const float*)d_in[2];
    const float* w2 = (const float*)d_in[3];
    const float* w3 = (const float*)d_in[4];
    float* out = (float*)d_out;
    int T = in_sizes[0] / H;   // 16384
    int P = T * 2;

    char* ws = (char*)d_ws;
    size_t off = 0;
    auto alloc = [&](size_t b) { size_t c = off; off = (off + b + 255) & ~(size_t)255; return c; };
    size_t misc_o  = alloc(256);
    int* counts  = (int*)(ws + misc_o);
    int* offsets = (int*)(ws + misc_o + 64);
    int* cursors = (int*)(ws + misc_o + 128);
    int* tileOff = (int*)(ws + misc_o + 192);
    size_t topi_o  = alloc((size_t)T * 2 * 4);
    size_t topw_o  = alloc((size_t)T * 2 * 4);
    size_t ptok_o  = alloc((size_t)P * 4);
    size_t pgate_o = alloc((size_t)P * 4);
    size_t inv_o   = alloc((size_t)T * 2 * 4);
    size_t wb_o  = alloc((size_t)3 * NW * 2);    // w1b | w3b | w2b contiguous
    size_t xg_o  = alloc((size_t)T * H * 2);     // token-order bf16 x
    size_t y_o   = alloc((size_t)P * H * 2);     // bf16 per-slot output
    u16* w1b = (u16*)(ws + wb_o);
    u16* w3b = w1b + NW;
    u16* w2b = w1b + 2 * (size_t)NW;

    // h buffer sized from the ACTUAL remaining workspace (256-row chunk tiles)
    int maxTiles = P / BM + E_N;            // 136
    size_t perTile = (size_t)BM * F * 2;    // 1 MB
    size_t avail = (ws_size > off + 256) ? (ws_size - off - 256) : 0;
    int tpc = (int)(avail / perTile);
    if (tpc > maxTiles) tpc = maxTiles;
    if (tpc < 4) tpc = 4;
    size_t h_o = alloc((size_t)tpc * perTile);

    hipMemsetAsync(ws + misc_o, 0, 256, stream);

    cvt3_kernel<<<8192, 256, 0, stream>>>(w1, w3, w2, w1b);
    router_kernel<<<T / 4, 256, 0, stream>>>(x, gw, (int*)(ws + topi_o), (float*)(ws + topw_o),
                                             (u16*)(ws + xg_o), T);
    hist_kernel<<<32, 256, 0, stream>>>((int*)(ws + topi_o), counts, P);
    scan_kernel<<<1, 64, 0, stream>>>(counts, offsets, cursors, tileOff);
    scatter_kernel<<<(P + 1023) / 1024, 1024, 0, stream>>>(
        (int*)(ws + topi_o), (float*)(ws + topw_o), cursors,
        (int*)(ws + ptok_o), (float*)(ws + pgate_o), (int*)(ws + inv_o), P);

    for (int cstart = 0; cstart < maxTiles; cstart += tpc) {
        int tpcThis = maxTiles - cstart; if (tpcThis > tpc) tpcThis = tpc;
        stage1_kernel<<<tpcThis * (F / 128), 512, 0, stream>>>(
            (u16*)(ws + xg_o), w1b, w3b,
            (int*)(ws + ptok_o), (float*)(ws + pgate_o), offsets, tileOff,
            (u16*)(ws + h_o), cstart, tpcThis);
        if (tpcThis * 4 >= 240)
            stage2_kernel<4><<<tpcThis * (H / 256), 512, 0, stream>>>(
                (u16*)(ws + h_o), w2b, offsets, tileOff,
                (u16*)(ws + y_o), cstart, tpcThis);
        else
            stage2_kernel<2><<<tpcThis * (H / 128), 512, 0, stream>>>(
                (u16*)(ws + h_o), w2b, offsets, tileOff,
                (u16*)(ws + y_o), cstart, tpcThis);
    }
    combine_kernel<<<T, 256, 0, stream>>>((u16*)(ws + y_o), (int*)(ws + inv_o), out);
}

// Round 14
// 685.780 us; speedup vs baseline: 1.1451x; 1.1451x over previous
//
#include <hip/hip_runtime.h>
#include <cstdint>

#define H 1024
#define F 2048
#define E_N 8
#define BM 256
#define BK 64
#define NW (E_N * F * H)

typedef __attribute__((ext_vector_type(8))) short short8v;
typedef __attribute__((ext_vector_type(4))) float float4v;
typedef unsigned short u16;

__device__ __forceinline__ u16 f2bf(float f) {
    uint32_t u = __float_as_uint(f);
    u += 0x7FFFu + ((u >> 16) & 1u);   // round-to-nearest-even
    return (u16)(u >> 16);
}
__device__ __forceinline__ float bf2f(u16 b) {
    return __uint_as_float(((uint32_t)b) << 16);
}

__device__ __forceinline__ void gload16(const void* g, void* l) {
    __builtin_amdgcn_global_load_lds((const __attribute__((address_space(1))) uint32_t*)g,
                                     (__attribute__((address_space(3))) uint32_t*)l, 16, 0, 0);
}

// raw barrier (no vmcnt drain) with compiler memory fence
__device__ __forceinline__ void barx() {
    asm volatile("" ::: "memory");
    __builtin_amdgcn_s_barrier();
    asm volatile("" ::: "memory");
}

// bijective XCD chunk swizzle (m204) + tile-mid / gy-inner order
__device__ __forceinline__ void decode_swz(int bid, int nTiles, int ngy, int gyc,
                                           int& tile, int& gy) {
    int nblk = nTiles * ngy;
    int q = nblk >> 3, r = nblk & 7;
    int xcd = bid & 7, pos = bid >> 3;
    int cid = (xcd < r ? xcd * (q + 1) : r * (q + 1) + (xcd - r) * q) + pos;
    int per = nTiles * gyc;
    int chunk = cid / per, rem = cid - chunk * per;
    tile = rem / gyc;
    gy = chunk * gyc + (rem - (rem / gyc) * gyc);
}

// ---------------- fp32 -> bf16, 3 weight tensors in one launch ----------------
__global__ __launch_bounds__(256) void cvt3_kernel(const float* __restrict__ s0,
                                                   const float* __restrict__ s1,
                                                   const float* __restrict__ s2,
                                                   u16* __restrict__ dst) {
    int i = (blockIdx.x * 256 + threadIdx.x) * 4;
    int stride = gridDim.x * 256 * 4;
    for (; i < 3 * NW; i += stride) {
        int seg = i / NW;
        int off = i - seg * NW;
        const float* s = (seg == 0) ? s0 : ((seg == 1) ? s1 : s2);
        float4 v = *(const float4*)(s + off);
        ushort4 o;
        o.x = f2bf(v.x); o.y = f2bf(v.y); o.z = f2bf(v.z); o.w = f2bf(v.w);
        *(ushort4*)(dst + i) = o;
    }
}

// ---------------- router (no atomics) + fused x->bf16 ----------------
__global__ __launch_bounds__(256) void router_kernel(const float* __restrict__ x,
                                                     const float* __restrict__ gw,
                                                     int* __restrict__ topi,
                                                     float* __restrict__ topw,
                                                     u16* __restrict__ xg, int T) {
    int wave = threadIdx.x >> 6, lane = threadIdx.x & 63;
    int t = blockIdx.x * 4 + wave;
    if (t >= T) return;
    const float4* xr = (const float4*)(x + (size_t)t * H);
    float4 xv[4];
#pragma unroll
    for (int i = 0; i < 4; i++) xv[i] = xr[i * 64 + lane];
#pragma unroll
    for (int i = 0; i < 4; i++) {
        ushort4 o;
        o.x = f2bf(xv[i].x); o.y = f2bf(xv[i].y);
        o.z = f2bf(xv[i].z); o.w = f2bf(xv[i].w);
        *(ushort4*)(xg + (size_t)t * H + (i * 64 + lane) * 4) = o;
    }
    float acc[E_N];
#pragma unroll
    for (int e = 0; e < E_N; e++) {
        const float4* gr = (const float4*)(gw + e * H);
        float s = 0.f;
#pragma unroll
        for (int i = 0; i < 4; i++) {
            float4 g = gr[i * 64 + lane];
            s += xv[i].x * g.x + xv[i].y * g.y + xv[i].z * g.z + xv[i].w * g.w;
        }
        acc[e] = s;
    }
#pragma unroll
    for (int e = 0; e < E_N; e++) {
#pragma unroll
        for (int off = 32; off; off >>= 1) acc[e] += __shfl_xor(acc[e], off, 64);
    }
    if (lane == 0) {
        int i0 = 0;
#pragma unroll
        for (int e = 1; e < E_N; e++) if (acc[e] > acc[i0]) i0 = e;
        int i1 = -1;
#pragma unroll
        for (int e = 0; e < E_N; e++) {
            if (e == i0) continue;
            if (i1 < 0 || acc[e] > acc[i1]) i1 = e;
        }
        float e1 = __expf(acc[i1] - acc[i0]);
        float w0 = 1.f / (1.f + e1);
        float w1v = e1 / (1.f + e1);
        topi[t * 2] = i0; topi[t * 2 + 1] = i1;
        topw[t * 2] = w0; topw[t * 2 + 1] = w1v;
    }
}

// ---------------- histogram: 8 global atomics per block ----------------
__global__ __launch_bounds__(256) void hist_kernel(const int* __restrict__ topi,
                                                   int* __restrict__ counts, int n) {
    __shared__ int hc[E_N];
    if (threadIdx.x < E_N) hc[threadIdx.x] = 0;
    __syncthreads();
    for (int i = blockIdx.x * 256 + threadIdx.x; i < n; i += gridDim.x * 256)
        atomicAdd(&hc[topi[i]], 1);
    __syncthreads();
    if (threadIdx.x < E_N) atomicAdd(&counts[threadIdx.x], hc[threadIdx.x]);
}

// ---------------- tiny serial scan ----------------
__global__ void scan_kernel(const int* __restrict__ counts, int* __restrict__ offsets,
                            int* __restrict__ cursors, int* __restrict__ tileOff) {
    if (threadIdx.x == 0 && blockIdx.x == 0) {
        int o = 0, to = 0;
        for (int e = 0; e < E_N; e++) {
            offsets[e] = o; cursors[e] = o; tileOff[e] = to;
            o += counts[e];
            to += (counts[e] + BM - 1) / BM;
        }
        offsets[E_N] = o; tileOff[E_N] = to;
    }
}

// ---------------- scatter: block-local ranks, 8 global atomics per block ----------------
__global__ __launch_bounds__(1024) void scatter_kernel(const int* __restrict__ topi,
                                                       const float* __restrict__ topw,
                                                       int* __restrict__ cursors,
                                                       int* __restrict__ perm_tok,
                                                       float* __restrict__ perm_gate,
                                                       int* __restrict__ inv, int n) {
    __shared__ int hc[E_N];
    __shared__ int base[E_N];
    int tid = threadIdx.x;
    if (tid < E_N) hc[tid] = 0;
    __syncthreads();
    int i = blockIdx.x * 1024 + tid;
    int e = 0, lrank = 0;
    bool ok = (i < n);
    if (ok) {
        e = topi[i];
        lrank = atomicAdd(&hc[e], 1);
    }
    __syncthreads();
    if (tid < E_N) base[tid] = atomicAdd(&cursors[tid], hc[tid]);
    __syncthreads();
    if (ok) {
        int pos = base[e] + lrank;
        perm_tok[pos] = i >> 1;
        perm_gate[pos] = topw[i];
        inv[i] = pos;
    }
}

// ---------------- stage 1: h = gate * silu(xg@w1^T) * (xg@w3^T) ----------------
// 256-row tile, BN=128 (dual w1/w3), 8 waves, counted-vmcnt schedule with only
// TWO barriers per K-tile (mid: vmcnt(6) -> this tile's late A; end: vmcnt(2) ->
// next tile's early 6 + buffer-swap WAR). Phases free-flow between barriers.
__global__ __launch_bounds__(512) void stage1_kernel(
    const u16* __restrict__ xg, const u16* __restrict__ w1b, const u16* __restrict__ w3b,
    const int* __restrict__ perm_tok, const float* __restrict__ perm_gate,
    const int* __restrict__ offsets, const int* __restrict__ tileOff,
    u16* __restrict__ h, int cstart, int tpcThis) {
    __shared__ u16 lA[2 * BM * BK];      // 64 KB, buf stride 16384 elems
    __shared__ u16 lB1[2 * 128 * BK];    // 32 KB, buf stride 8192
    __shared__ u16 lB3[2 * 128 * BK];    // 32 KB
    __shared__ int ptokS[BM];
    __shared__ float pgateS[BM];

    int tileL, nbIdx;
    decode_swz(blockIdx.x, tpcThis, F / 128, 4, tileL, nbIdx);
    int tile = cstart + tileL;
    if (tile >= tileOff[E_N]) return;
    int e = 0;
    while (e < E_N - 1 && tile >= tileOff[e + 1]) e++;
    int rbase = offsets[e] + (tile - tileOff[e]) * BM;
    int segEnd = offsets[e + 1];
    int e0 = 0;
    while (e0 < E_N - 1 && cstart >= tileOff[e0 + 1]) e0++;
    int chunkBase = offsets[e0] + (cstart - tileOff[e0]) * BM;

    int tid = threadIdx.x;
    if (tid < BM) {
        int p = rbase + tid; if (p > segEnd - 1) p = segEnd - 1;
        ptokS[tid] = perm_tok[p];
        pgateS[tid] = perm_gate[p];
    }
    __syncthreads();

    int lane = tid & 63, wid = tid >> 6;
    int wr = wid >> 2, wc = wid & 3;
    int lrow = lane & 15, kgrp = lane >> 4;
    int lr = lane >> 3, csw = ((lane & 7) ^ lr) << 3;
    int nb = nbIdx * 128;
    const u16* w1p = w1b + (size_t)e * F * H + (size_t)nb * H;
    const u16* w3p = w3b + (size_t)e * F * H + (size_t)nb * H;

    // global stage pointers (swizzled-source; advance +BK per K-tile)
    const u16* pA[4];
#pragma unroll
    for (int j = 0; j < 4; j++) pA[j] = xg + (size_t)ptokS[(j * 8 + wid) * 8 + lr] * H + csw;
    const u16 *pB1[2], *pB3[2];
#pragma unroll
    for (int j = 0; j < 2; j++) {
        int rr = (j * 8 + wid) * 8 + lr;
        pB1[j] = w1p + (size_t)rr * H + csw;
        pB3[j] = w3p + (size_t)rr * H + csw;
    }

    // hoisted ds_read element bases (r&7 == lrow&7 for all fragment rows)
    int swe0 = (kgrp ^ (lrow & 7)) << 3;
    int swe1 = ((4 + kgrp) ^ (lrow & 7)) << 3;
    int eA0 = (wr * 128 + lrow) * BK + swe0;
    int eA1 = (wr * 128 + lrow) * BK + swe1;
    int eB0 = (wc * 32 + lrow) * BK + swe0;
    int eB1 = (wc * 32 + lrow) * BK + swe1;

#define STA(CC, j)  gload16(pA[j],  &lA[(CC) * 16384 + ((j) * 8 + wid) * 8 * BK])
#define STB1(CC, j) gload16(pB1[j], &lB1[(CC) * 8192 + ((j) * 8 + wid) * 8 * BK])
#define STB3(CC, j) gload16(pB3[j], &lB3[(CC) * 8192 + ((j) * 8 + wid) * 8 * BK])

    float4v acc1[8][2], acc3[8][2];
#pragma unroll
    for (int a = 0; a < 8; a++)
#pragma unroll
        for (int b = 0; b < 2; b++) { acc1[a][b] = (float4v)(0.f); acc3[a][b] = (float4v)(0.f); }

    // prologue: tile 0 into buf 0; A j1,j3 issued LAST (entry invariant = 2 outstanding)
    STB1(0, 0); STB1(0, 1);
    STB3(0, 0); STB3(0, 1);
    STA(0, 0); STA(0, 2); STA(0, 1); STA(0, 3);
#pragma unroll
    for (int j = 0; j < 4; j++) pA[j] += BK;
    pB1[0] += BK; pB1[1] += BK; pB3[0] += BK; pB3[1] += BK;
    asm volatile("s_waitcnt vmcnt(2)" ::: "memory");
    barx();

#define S1_DSA(CC, p) \
    short8v aF[2][2]; \
    _Pragma("unroll") \
    for (int pm = 0; pm < 2; pm++) { \
        aF[pm][0] = *(const short8v*)&lA[eA0 + (CC) * 16384 + (2 * (p) + pm) * 1024]; \
        aF[pm][1] = *(const short8v*)&lA[eA1 + (CC) * 16384 + (2 * (p) + pm) * 1024]; \
    }
#define S1_MM(p) \
    __builtin_amdgcn_s_setprio(1); \
    _Pragma("unroll") \
    for (int pm = 0; pm < 2; pm++) \
    _Pragma("unroll") \
    for (int n = 0; n < 2; n++) \
    _Pragma("unroll") \
    for (int kk = 0; kk < 2; kk++) { \
        acc1[2 * (p) + pm][n] = __builtin_amdgcn_mfma_f32_16x16x32_bf16(aF[pm][kk], b1F[n][kk], acc1[2 * (p) + pm][n], 0, 0, 0); \
        acc3[2 * (p) + pm][n] = __builtin_amdgcn_mfma_f32_16x16x32_bf16(aF[pm][kk], b3F[n][kk], acc3[2 * (p) + pm][n], 0, 0, 0); \
    } \
    __builtin_amdgcn_s_setprio(0);

// 2 barriers per K-tile: mid (after phases 0-1, vmcnt(6)) and end (vmcnt(2)).
#define S1_KT(CC, LAST) { \
    short8v b1F[2][2], b3F[2][2]; \
    _Pragma("unroll") \
    for (int n = 0; n < 2; n++) { \
        b1F[n][0] = *(const short8v*)&lB1[eB0 + (CC) * 8192 + n * 1024]; \
        b1F[n][1] = *(const short8v*)&lB1[eB1 + (CC) * 8192 + n * 1024]; \
        b3F[n][0] = *(const short8v*)&lB3[eB0 + (CC) * 8192 + n * 1024]; \
        b3F[n][1] = *(const short8v*)&lB3[eB1 + (CC) * 8192 + n * 1024]; \
    } \
    { S1_DSA(CC, 0) \
      if (!(LAST)) { STB1((CC) ^ 1, 0); STB1((CC) ^ 1, 1); STA((CC) ^ 1, 0); } \
      S1_MM(0) } \
    { S1_DSA(CC, 1) \
      if (!(LAST)) { STB3((CC) ^ 1, 0); STB3((CC) ^ 1, 1); STA((CC) ^ 1, 2); } \
      S1_MM(1) } \
    if (!(LAST)) { asm volatile("s_waitcnt vmcnt(6)" ::: "memory"); } \
    else         { asm volatile("s_waitcnt vmcnt(0)" ::: "memory"); } \
    barx(); \
    { S1_DSA(CC, 2) \
      if (!(LAST)) { STA((CC) ^ 1, 1); } \
      S1_MM(2) } \
    { S1_DSA(CC, 3) \
      if (!(LAST)) { STA((CC) ^ 1, 3); } \
      S1_MM(3) } \
    if (!(LAST)) { asm volatile("s_waitcnt vmcnt(2)" ::: "memory"); } \
    else         { asm volatile("s_waitcnt vmcnt(0)" ::: "memory"); } \
    barx(); \
    _Pragma("unroll") \
    for (int j = 0; j < 4; j++) pA[j] += BK; \
    pB1[0] += BK; pB1[1] += BK; pB3[0] += BK; pB3[1] += BK; \
}

    // NT = H/BK = 16 K-tiles, unrolled x2 for compile-time buffer index
    for (int tt = 0; tt < (H / BK) - 2; tt += 2) {
        S1_KT(0, false)
        S1_KT(1, false)
    }
    S1_KT(0, false)
    S1_KT(1, true)
#undef S1_DSA
#undef S1_MM
#undef S1_KT
#undef STA
#undef STB1
#undef STB3

    int rif = (lane >> 4) * 4;
#pragma unroll
    for (int m = 0; m < 8; m++) {
#pragma unroll
        for (int reg = 0; reg < 4; reg++) {
            int rowIdx = wr * 128 + m * 16 + rif + reg;
            int p = rbase + rowIdx;
            if (p < segEnd) {
                float g = pgateS[rowIdx];
#pragma unroll
                for (int n = 0; n < 2; n++) {
                    float a1 = acc1[m][n][reg], a3 = acc3[m][n][reg];
                    float sv = a1 / (1.f + __expf(-a1));
                    float hv = sv * a3 * g;
                    int ncol = nb + wc * 32 + n * 16 + (lane & 15);
                    h[(size_t)(p - chunkBase) * F + ncol] = f2bf(hv);
                }
            }
        }
    }
}

// ---------------- stage 2: y[p] = h[p] @ w2^T ----------------
// 256-row tile, BN = NREP*64, 8 waves, 2 barriers per K-tile (same invariants)
template<int NREP>
__global__ __launch_bounds__(512) void stage2_kernel(
    const u16* __restrict__ h, const u16* __restrict__ w2b,
    const int* __restrict__ offsets, const int* __restrict__ tileOff,
    u16* __restrict__ y, int cstart, int tpcThis) {
    constexpr int BN = NREP * 64;
    constexpr int BSTRIDE = BN * BK;       // elems per buf
    __shared__ u16 lA[2 * BM * BK];
    __shared__ u16 lB[2 * BSTRIDE];

    int tileL, nbIdx;
    decode_swz(blockIdx.x, tpcThis, H / BN, 4, tileL, nbIdx);
    int tile = cstart + tileL;
    if (tile >= tileOff[E_N]) return;
    int e = 0;
    while (e < E_N - 1 && tile >= tileOff[e + 1]) e++;
    int rbase = offsets[e] + (tile - tileOff[e]) * BM;
    int segEnd = offsets[e + 1];
    int e0 = 0;
    while (e0 < E_N - 1 && cstart >= tileOff[e0 + 1]) e0++;
    int chunkBase = offsets[e0] + (cstart - tileOff[e0]) * BM;

    int tid = threadIdx.x;
    int lane = tid & 63, wid = tid >> 6;
    int wr = wid >> 2, wc = wid & 3;
    int lrow = lane & 15, kgrp = lane >> 4;
    int lr = lane >> 3, csw = ((lane & 7) ^ lr) << 3;
    int nb = nbIdx * BN;
    const u16* w2p = w2b + (size_t)e * H * F + (size_t)nb * F;

    const u16* pA[4];
#pragma unroll
    for (int j = 0; j < 4; j++) {
        int rb = (j * 8 + wid) * 8;
        int p = rbase + rb + lr; if (p > segEnd - 1) p = segEnd - 1;
        pA[j] = h + (size_t)(p - chunkBase) * F + csw;
    }
    const u16* pB[NREP];
#pragma unroll
    for (int j = 0; j < NREP; j++) pB[j] = w2p + (size_t)((j * 8 + wid) * 8 + lr) * F + csw;

    int swe0 = (kgrp ^ (lrow & 7)) << 3;
    int swe1 = ((4 + kgrp) ^ (lrow & 7)) << 3;
    int eA0 = (wr * 128 + lrow) * BK + swe0;
    int eA1 = (wr * 128 + lrow) * BK + swe1;
    int eB0 = (wc * (NREP * 16) + lrow) * BK + swe0;
    int eB1 = (wc * (NREP * 16) + lrow) * BK + swe1;

#define STA2(CC, j) gload16(pA[j], &lA[(CC) * 16384 + ((j) * 8 + wid) * 8 * BK])
#define STB2(CC, j) gload16(pB[j], &lB[(CC) * BSTRIDE + ((j) * 8 + wid) * 8 * BK])

    float4v acc[8][NREP];
#pragma unroll
    for (int a = 0; a < 8; a++)
#pragma unroll
        for (int b = 0; b < NREP; b++) acc[a][b] = (float4v)(0.f);

    // prologue: A j1,j3 issued LAST (entry invariant = 2 outstanding)
#pragma unroll
    for (int j = 0; j < NREP; j++) STB2(0, j);
    STA2(0, 0); STA2(0, 2); STA2(0, 1); STA2(0, 3);
#pragma unroll
    for (int j = 0; j < 4; j++) pA[j] += BK;
#pragma unroll
    for (int j = 0; j < NREP; j++) pB[j] += BK;
    asm volatile("s_waitcnt vmcnt(2)" ::: "memory");
    barx();

#define S2_DSA(CC, p) \
    short8v aF[2][2]; \
    _Pragma("unroll") \
    for (int pm = 0; pm < 2; pm++) { \
        aF[pm][0] = *(const short8v*)&lA[eA0 + (CC) * 16384 + (2 * (p) + pm) * 1024]; \
        aF[pm][1] = *(const short8v*)&lA[eA1 + (CC) * 16384 + (2 * (p) + pm) * 1024]; \
    }
#define S2_MM(p) \
    __builtin_amdgcn_s_setprio(1); \
    _Pragma("unroll") \
    for (int pm = 0; pm < 2; pm++) \
    _Pragma("unroll") \
    for (int n = 0; n < NREP; n++) \
    _Pragma("unroll") \
    for (int kk = 0; kk < 2; kk++) \
        acc[2 * (p) + pm][n] = __builtin_amdgcn_mfma_f32_16x16x32_bf16(aF[pm][kk], bF[n][kk], acc[2 * (p) + pm][n], 0, 0, 0); \
    __builtin_amdgcn_s_setprio(0);

// 2 barriers per K-tile (mid vmcnt(6|4), end vmcnt(2))
#define S2_KT(CC, LAST) { \
    short8v bF[NREP][2]; \
    _Pragma("unroll") \
    for (int n = 0; n < NREP; n++) { \
        bF[n][0] = *(const short8v*)&lB[eB0 + (CC) * BSTRIDE + n * 1024]; \
        bF[n][1] = *(const short8v*)&lB[eB1 + (CC) * BSTRIDE + n * 1024]; \
    } \
    { S2_DSA(CC, 0) \
      if (!(LAST)) { STB2((CC) ^ 1, 0); if (NREP == 4) STB2((CC) ^ 1, 1); STA2((CC) ^ 1, 0); } \
      S2_MM(0) } \
    { S2_DSA(CC, 1) \
      if (!(LAST)) { if (NREP == 4) { STB2((CC) ^ 1, 2); STB2((CC) ^ 1, 3); } else STB2((CC) ^ 1, 1); \
                     STA2((CC) ^ 1, 2); } \
      S2_MM(1) } \
    if (!(LAST)) { \
        if (NREP == 4) { asm volatile("s_waitcnt vmcnt(6)" ::: "memory"); } \
        else           { asm volatile("s_waitcnt vmcnt(4)" ::: "memory"); } \
    } else { asm volatile("s_waitcnt vmcnt(0)" ::: "memory"); } \
    barx(); \
    { S2_DSA(CC, 2) \
      if (!(LAST)) { STA2((CC) ^ 1, 1); } \
      S2_MM(2) } \
    { S2_DSA(CC, 3) \
      if (!(LAST)) { STA2((CC) ^ 1, 3); } \
      S2_MM(3) } \
    if (!(LAST)) { asm volatile("s_waitcnt vmcnt(2)" ::: "memory"); } \
    else         { asm volatile("s_waitcnt vmcnt(0)" ::: "memory"); } \
    barx(); \
    _Pragma("unroll") \
    for (int j = 0; j < 4; j++) pA[j] += BK; \
    _Pragma("unroll") \
    for (int j = 0; j < NREP; j++) pB[j] += BK; \
}

    for (int tt = 0; tt < (F / BK) - 2; tt += 2) {
        S2_KT(0, false)
        S2_KT(1, false)
    }
    S2_KT(0, false)
    S2_KT(1, true)
#undef S2_DSA
#undef S2_MM
#undef S2_KT
#undef STA2
#undef STB2

    int rif = (lane >> 4) * 4;
#pragma unroll
    for (int m = 0; m < 8; m++) {
#pragma unroll
        for (int reg = 0; reg < 4; reg++) {
            int rowIdx = wr * 128 + m * 16 + rif + reg;
            int p = rbase + rowIdx;
            if (p < segEnd) {
#pragma unroll
                for (int n = 0; n < NREP; n++) {
                    int col = nb + wc * (BN / 4) + n * 16 + (lane & 15);
                    y[(size_t)p * H + col] = f2bf(acc[m][n][reg]);
                }
            }
        }
    }
}

// ---------------- combine: out[t] = y[slot0] + y[slot1] ----------------
__global__ __launch_bounds__(256) void combine_kernel(const u16* __restrict__ y,
                                                      const int* __restrict__ inv,
                                                      float* __restrict__ out) {
    int t = blockIdx.x, c = threadIdx.x;
    int s0 = inv[t * 2], s1 = inv[t * 2 + 1];
    ushort4 a = *(const ushort4*)(y + (size_t)s0 * H + c * 4);
    ushort4 b = *(const ushort4*)(y + (size_t)s1 * H + c * 4);
    float4 o;
    o.x = bf2f(a.x) + bf2f(b.x);
    o.y = bf2f(a.y) + bf2f(b.y);
    o.z = bf2f(a.z) + bf2f(b.z);
    o.w = bf2f(a.w) + bf2f(b.w);
    *(float4*)(out + (size_t)t * H + c * 4) = o;
}

extern "C" void kernel_launch(void* const* d_in, const int* in_sizes, int n_in,
                              void* d_out, int out_size, void* d_ws, size_t ws_size,
                              hipStream_t stream) {
    (void)n_in; (void)out_size;
    const float* x  = (const float*)d_in[0];
    const float* gw = (const float*)d_in[1];
    const float* w1 = (const float*)d_in[2];
    const float* w2 = (const float*)d_in[3];
    const float* w3 = (const float*)d_in[4];
    float* out = (float*)d_out;
    int T = in_sizes[0] / H;   // 16384
    int P = T * 2;

    char* ws = (char*)d_ws;
    size_t off = 0;
    auto alloc = [&](size_t b) { size_t c = off; off = (off + b + 255) & ~(size_t)255; return c; };
    size_t misc_o  = alloc(256);
    int* counts  = (int*)(ws + misc_o);
    int* offsets = (int*)(ws + misc_o + 64);
    int* cursors = (int*)(ws + misc_o + 128);
    int* tileOff = (int*)(ws + misc_o + 192);
    size_t topi_o  = alloc((size_t)T * 2 * 4);
    size_t topw_o  = alloc((size_t)T * 2 * 4);
    size_t ptok_o  = alloc((size_t)P * 4);
    size_t pgate_o = alloc((size_t)P * 4);
    size_t inv_o   = alloc((size_t)T * 2 * 4);
    size_t wb_o  = alloc((size_t)3 * NW * 2);    // w1b | w3b | w2b contiguous
    size_t xg_o  = alloc((size_t)T * H * 2);     // token-order bf16 x
    size_t y_o   = alloc((size_t)P * H * 2);     // bf16 per-slot output
    u16* w1b = (u16*)(ws + wb_o);
    u16* w3b = w1b + NW;
    u16* w2b = w1b + 2 * (size_t)NW;

    // h buffer: max tiles that fit, then BALANCE chunks (62/62/12 -> 46/46/44)
    int maxTiles = P / BM + E_N;            // 136
    size_t perTile = (size_t)BM * F * 2;    // 1 MB
    size_t avail = (ws_size > off + 256) ? (ws_size - off - 256) : 0;
    int tpcMax = (int)(avail / perTile);
    if (tpcMax > maxTiles) tpcMax = maxTiles;
    if (tpcMax < 4) tpcMax = 4;
    int nch = (maxTiles + tpcMax - 1) / tpcMax;
    int tpc = (maxTiles + nch - 1) / nch;
    size_t h_o = alloc((size_t)tpc * perTile);

    hipMemsetAsync(ws + misc_o, 0, 256, stream);

    cvt3_kernel<<<8192, 256, 0, stream>>>(w1, w3, w2, w1b);
    router_kernel<<<T / 4, 256, 0, stream>>>(x, gw, (int*)(ws + topi_o), (float*)(ws + topw_o),
                                             (u16*)(ws + xg_o), T);
    hist_kernel<<<32, 256, 0, stream>>>((int*)(ws + topi_o), counts, P);
    scan_kernel<<<1, 64, 0, stream>>>(counts, offsets, cursors, tileOff);
    scatter_kernel<<<(P + 1023) / 1024, 1024, 0, stream>>>(
        (int*)(ws + topi_o), (float*)(ws + topw_o), cursors,
        (int*)(ws + ptok_o), (float*)(ws + pgate_o), (int*)(ws + inv_o), P);

    for (int cstart = 0; cstart < maxTiles; cstart += tpc) {
        int tpcThis = maxTiles - cstart; if (tpcThis > tpc) tpcThis = tpc;
        stage1_kernel<<<tpcThis * (F / 128), 512, 0, stream>>>(
            (u16*)(ws + xg_o), w1b, w3b,
            (int*)(ws + ptok_o), (float*)(ws + pgate_o), offsets, tileOff,
            (u16*)(ws + h_o), cstart, tpcThis);
        if (tpcThis * 4 >= 240)
            stage2_kernel<4><<<tpcThis * (H / 256), 512, 0, stream>>>(
                (u16*)(ws + h_o), w2b, offsets, tileOff,
                (u16*)(ws + y_o), cstart, tpcThis);
        else
            stage2_kernel<2><<<tpcThis * (H / 128), 512, 0, stream>>>(
                (u16*)(ws + h_o), w2b, offsets, tileOff,
                (u16*)(ws + y_o), cstart, tpcThis);
    }
    combine_kernel<<<T, 256, 0, stream>>>((u16*)(ws + y_o), (int*)(ws + inv_o), out);
}

// Round 15
// 609.416 us; speedup vs baseline: 1.2885x; 1.1253x over previous
//
#include <hip/hip_runtime.h>
#include <cstdint>

#define H 1024
#define F 2048
#define E_N 8
#define BM 256
#define BK 64
#define NW (E_N * F * H)

typedef __attribute__((ext_vector_type(8))) short short8v;
typedef __attribute__((ext_vector_type(4))) float float4v;
typedef unsigned short u16;

__device__ __forceinline__ u16 f2bf(float f) {
    uint32_t u = __float_as_uint(f);
    u += 0x7FFFu + ((u >> 16) & 1u);   // round-to-nearest-even
    return (u16)(u >> 16);
}
__device__ __forceinline__ float bf2f(u16 b) {
    return __uint_as_float(((uint32_t)b) << 16);
}

__device__ __forceinline__ void gload16(const void* g, void* l) {
    __builtin_amdgcn_global_load_lds((const __attribute__((address_space(1))) uint32_t*)g,
                                     (__attribute__((address_space(3))) uint32_t*)l, 16, 0, 0);
}

// raw barrier (no vmcnt drain) with compiler memory fence
__device__ __forceinline__ void barx() {
    asm volatile("" ::: "memory");
    __builtin_amdgcn_s_barrier();
    asm volatile("" ::: "memory");
}

// bijective XCD chunk swizzle (m204) + tile-mid / gy-inner order
__device__ __forceinline__ void decode_swz(int bid, int nTiles, int ngy, int gyc,
                                           int& tile, int& gy) {
    int nblk = nTiles * ngy;
    int q = nblk >> 3, r = nblk & 7;
    int xcd = bid & 7, pos = bid >> 3;
    int cid = (xcd < r ? xcd * (q + 1) : r * (q + 1) + (xcd - r) * q) + pos;
    int per = nTiles * gyc;
    int chunk = cid / per, rem = cid - chunk * per;
    tile = rem / gyc;
    gy = chunk * gyc + (rem - (rem / gyc) * gyc);
}

// ---------------- fp32 -> bf16, 3 weight tensors in one launch ----------------
__global__ __launch_bounds__(256) void cvt3_kernel(const float* __restrict__ s0,
                                                   const float* __restrict__ s1,
                                                   const float* __restrict__ s2,
                                                   u16* __restrict__ dst) {
    int i = (blockIdx.x * 256 + threadIdx.x) * 4;
    int stride = gridDim.x * 256 * 4;
    for (; i < 3 * NW; i += stride) {
        int seg = i / NW;
        int off = i - seg * NW;
        const float* s = (seg == 0) ? s0 : ((seg == 1) ? s1 : s2);
        float4 v = *(const float4*)(s + off);
        ushort4 o;
        o.x = f2bf(v.x); o.y = f2bf(v.y); o.z = f2bf(v.z); o.w = f2bf(v.w);
        *(ushort4*)(dst + i) = o;
    }
}

// ---------------- router (no atomics) + fused x->bf16 ----------------
__global__ __launch_bounds__(256) void router_kernel(const float* __restrict__ x,
                                                     const float* __restrict__ gw,
                                                     int* __restrict__ topi,
                                                     float* __restrict__ topw,
                                                     u16* __restrict__ xg, int T) {
    int wave = threadIdx.x >> 6, lane = threadIdx.x & 63;
    int t = blockIdx.x * 4 + wave;
    if (t >= T) return;
    const float4* xr = (const float4*)(x + (size_t)t * H);
    float4 xv[4];
#pragma unroll
    for (int i = 0; i < 4; i++) xv[i] = xr[i * 64 + lane];
#pragma unroll
    for (int i = 0; i < 4; i++) {
        ushort4 o;
        o.x = f2bf(xv[i].x); o.y = f2bf(xv[i].y);
        o.z = f2bf(xv[i].z); o.w = f2bf(xv[i].w);
        *(ushort4*)(xg + (size_t)t * H + (i * 64 + lane) * 4) = o;
    }
    float acc[E_N];
#pragma unroll
    for (int e = 0; e < E_N; e++) {
        const float4* gr = (const float4*)(gw + e * H);
        float s = 0.f;
#pragma unroll
        for (int i = 0; i < 4; i++) {
            float4 g = gr[i * 64 + lane];
            s += xv[i].x * g.x + xv[i].y * g.y + xv[i].z * g.z + xv[i].w * g.w;
        }
        acc[e] = s;
    }
#pragma unroll
    for (int e = 0; e < E_N; e++) {
#pragma unroll
        for (int off = 32; off; off >>= 1) acc[e] += __shfl_xor(acc[e], off, 64);
    }
    if (lane == 0) {
        int i0 = 0;
#pragma unroll
        for (int e = 1; e < E_N; e++) if (acc[e] > acc[i0]) i0 = e;
        int i1 = -1;
#pragma unroll
        for (int e = 0; e < E_N; e++) {
            if (e == i0) continue;
            if (i1 < 0 || acc[e] > acc[i1]) i1 = e;
        }
        float e1 = __expf(acc[i1] - acc[i0]);
        float w0 = 1.f / (1.f + e1);
        float w1v = e1 / (1.f + e1);
        topi[t * 2] = i0; topi[t * 2 + 1] = i1;
        topw[t * 2] = w0; topw[t * 2 + 1] = w1v;
    }
}

// ---------------- histogram: 8 global atomics per block ----------------
__global__ __launch_bounds__(256) void hist_kernel(const int* __restrict__ topi,
                                                   int* __restrict__ counts, int n) {
    __shared__ int hc[E_N];
    if (threadIdx.x < E_N) hc[threadIdx.x] = 0;
    __syncthreads();
    for (int i = blockIdx.x * 256 + threadIdx.x; i < n; i += gridDim.x * 256)
        atomicAdd(&hc[topi[i]], 1);
    __syncthreads();
    if (threadIdx.x < E_N) atomicAdd(&counts[threadIdx.x], hc[threadIdx.x]);
}

// ---------------- tiny serial scan ----------------
__global__ void scan_kernel(const int* __restrict__ counts, int* __restrict__ offsets,
                            int* __restrict__ cursors, int* __restrict__ tileOff) {
    if (threadIdx.x == 0 && blockIdx.x == 0) {
        int o = 0, to = 0;
        for (int e = 0; e < E_N; e++) {
            offsets[e] = o; cursors[e] = o; tileOff[e] = to;
            o += counts[e];
            to += (counts[e] + BM - 1) / BM;
        }
        offsets[E_N] = o; tileOff[E_N] = to;
    }
}

// ---------------- scatter: block-local ranks, 8 global atomics per block ----------------
__global__ __launch_bounds__(1024) void scatter_kernel(const int* __restrict__ topi,
                                                       const float* __restrict__ topw,
                                                       int* __restrict__ cursors,
                                                       int* __restrict__ perm_tok,
                                                       float* __restrict__ perm_gate,
                                                       int* __restrict__ inv, int n) {
    __shared__ int hc[E_N];
    __shared__ int base[E_N];
    int tid = threadIdx.x;
    if (tid < E_N) hc[tid] = 0;
    __syncthreads();
    int i = blockIdx.x * 1024 + tid;
    int e = 0, lrank = 0;
    bool ok = (i < n);
    if (ok) {
        e = topi[i];
        lrank = atomicAdd(&hc[e], 1);
    }
    __syncthreads();
    if (tid < E_N) base[tid] = atomicAdd(&cursors[tid], hc[tid]);
    __syncthreads();
    if (ok) {
        int pos = base[e] + lrank;
        perm_tok[pos] = i >> 1;
        perm_gate[pos] = topw[i];
        inv[i] = pos;
    }
}

// ---------------- stage 1: h = gate * silu(xg@w1^T) * (xg@w3^T) ----------------
// 256-row tile, BN=128 (dual w1/w3), 8 waves, counted-vmcnt schedule with only
// TWO barriers per K-tile (mid: vmcnt(6) -> this tile's late A; end: vmcnt(2) ->
// next tile's early 6 + buffer-swap WAR). Phases free-flow between barriers.
__global__ __launch_bounds__(512) void stage1_kernel(
    const u16* __restrict__ xg, const u16* __restrict__ w1b, const u16* __restrict__ w3b,
    const int* __restrict__ perm_tok, const float* __restrict__ perm_gate,
    const int* __restrict__ offsets, const int* __restrict__ tileOff,
    u16* __restrict__ h, int cstart, int tpcThis) {
    __shared__ u16 lA[2 * BM * BK];      // 64 KB, buf stride 16384 elems
    __shared__ u16 lB1[2 * 128 * BK];    // 32 KB, buf stride 8192
    __shared__ u16 lB3[2 * 128 * BK];    // 32 KB
    __shared__ int ptokS[BM];
    __shared__ float pgateS[BM];

    int tileL, nbIdx;
    decode_swz(blockIdx.x, tpcThis, F / 128, 4, tileL, nbIdx);
    int tile = cstart + tileL;
    if (tile >= tileOff[E_N]) return;
    int e = 0;
    while (e < E_N - 1 && tile >= tileOff[e + 1]) e++;
    int rbase = offsets[e] + (tile - tileOff[e]) * BM;
    int segEnd = offsets[e + 1];
    int e0 = 0;
    while (e0 < E_N - 1 && cstart >= tileOff[e0 + 1]) e0++;
    int chunkBase = offsets[e0] + (cstart - tileOff[e0]) * BM;

    int tid = threadIdx.x;
    if (tid < BM) {
        int p = rbase + tid; if (p > segEnd - 1) p = segEnd - 1;
        ptokS[tid] = perm_tok[p];
        pgateS[tid] = perm_gate[p];
    }
    __syncthreads();

    int lane = tid & 63, wid = tid >> 6;
    int wr = wid >> 2, wc = wid & 3;
    int lrow = lane & 15, kgrp = lane >> 4;
    int lr = lane >> 3, csw = ((lane & 7) ^ lr) << 3;
    int nb = nbIdx * 128;
    const u16* w1p = w1b + (size_t)e * F * H + (size_t)nb * H;
    const u16* w3p = w3b + (size_t)e * F * H + (size_t)nb * H;

    // global stage pointers (swizzled-source; advance +BK per K-tile)
    const u16* pA[4];
#pragma unroll
    for (int j = 0; j < 4; j++) pA[j] = xg + (size_t)ptokS[(j * 8 + wid) * 8 + lr] * H + csw;
    const u16 *pB1[2], *pB3[2];
#pragma unroll
    for (int j = 0; j < 2; j++) {
        int rr = (j * 8 + wid) * 8 + lr;
        pB1[j] = w1p + (size_t)rr * H + csw;
        pB3[j] = w3p + (size_t)rr * H + csw;
    }

    // hoisted ds_read element bases (r&7 == lrow&7 for all fragment rows)
    int swe0 = (kgrp ^ (lrow & 7)) << 3;
    int swe1 = ((4 + kgrp) ^ (lrow & 7)) << 3;
    int eA0 = (wr * 128 + lrow) * BK + swe0;
    int eA1 = (wr * 128 + lrow) * BK + swe1;
    int eB0 = (wc * 32 + lrow) * BK + swe0;
    int eB1 = (wc * 32 + lrow) * BK + swe1;

#define STA(CC, j)  gload16(pA[j],  &lA[(CC) * 16384 + ((j) * 8 + wid) * 8 * BK])
#define STB1(CC, j) gload16(pB1[j], &lB1[(CC) * 8192 + ((j) * 8 + wid) * 8 * BK])
#define STB3(CC, j) gload16(pB3[j], &lB3[(CC) * 8192 + ((j) * 8 + wid) * 8 * BK])

    float4v acc1[8][2], acc3[8][2];
#pragma unroll
    for (int a = 0; a < 8; a++)
#pragma unroll
        for (int b = 0; b < 2; b++) { acc1[a][b] = (float4v)(0.f); acc3[a][b] = (float4v)(0.f); }

    // prologue: tile 0 into buf 0; A j1,j3 issued LAST (entry invariant = 2 outstanding)
    STB1(0, 0); STB1(0, 1);
    STB3(0, 0); STB3(0, 1);
    STA(0, 0); STA(0, 2); STA(0, 1); STA(0, 3);
#pragma unroll
    for (int j = 0; j < 4; j++) pA[j] += BK;
    pB1[0] += BK; pB1[1] += BK; pB3[0] += BK; pB3[1] += BK;
    asm volatile("s_waitcnt vmcnt(2)" ::: "memory");
    barx();

#define S1_DSA(CC, p) \
    short8v aF[2][2]; \
    _Pragma("unroll") \
    for (int pm = 0; pm < 2; pm++) { \
        aF[pm][0] = *(const short8v*)&lA[eA0 + (CC) * 16384 + (2 * (p) + pm) * 1024]; \
        aF[pm][1] = *(const short8v*)&lA[eA1 + (CC) * 16384 + (2 * (p) + pm) * 1024]; \
    }
#define S1_MM(p) \
    __builtin_amdgcn_s_setprio(1); \
    _Pragma("unroll") \
    for (int pm = 0; pm < 2; pm++) \
    _Pragma("unroll") \
    for (int n = 0; n < 2; n++) \
    _Pragma("unroll") \
    for (int kk = 0; kk < 2; kk++) { \
        acc1[2 * (p) + pm][n] = __builtin_amdgcn_mfma_f32_16x16x32_bf16(aF[pm][kk], b1F[n][kk], acc1[2 * (p) + pm][n], 0, 0, 0); \
        acc3[2 * (p) + pm][n] = __builtin_amdgcn_mfma_f32_16x16x32_bf16(aF[pm][kk], b3F[n][kk], acc3[2 * (p) + pm][n], 0, 0, 0); \
    } \
    __builtin_amdgcn_s_setprio(0);

// 2 barriers per K-tile: mid (after phases 0-1, vmcnt(6)) and end (vmcnt(2)).
#define S1_KT(CC, LAST) { \
    short8v b1F[2][2], b3F[2][2]; \
    _Pragma("unroll") \
    for (int n = 0; n < 2; n++) { \
        b1F[n][0] = *(const short8v*)&lB1[eB0 + (CC) * 8192 + n * 1024]; \
        b1F[n][1] = *(const short8v*)&lB1[eB1 + (CC) * 8192 + n * 1024]; \
        b3F[n][0] = *(const short8v*)&lB3[eB0 + (CC) * 8192 + n * 1024]; \
        b3F[n][1] = *(const short8v*)&lB3[eB1 + (CC) * 8192 + n * 1024]; \
    } \
    { S1_DSA(CC, 0) \
      if (!(LAST)) { STB1((CC) ^ 1, 0); STB1((CC) ^ 1, 1); STA((CC) ^ 1, 0); } \
      S1_MM(0) } \
    { S1_DSA(CC, 1) \
      if (!(LAST)) { STB3((CC) ^ 1, 0); STB3((CC) ^ 1, 1); STA((CC) ^ 1, 2); } \
      S1_MM(1) } \
    if (!(LAST)) { asm volatile("s_waitcnt vmcnt(6)" ::: "memory"); } \
    else         { asm volatile("s_waitcnt vmcnt(0)" ::: "memory"); } \
    barx(); \
    { S1_DSA(CC, 2) \
      if (!(LAST)) { STA((CC) ^ 1, 1); } \
      S1_MM(2) } \
    { S1_DSA(CC, 3) \
      if (!(LAST)) { STA((CC) ^ 1, 3); } \
      S1_MM(3) } \
    if (!(LAST)) { asm volatile("s_waitcnt vmcnt(2)" ::: "memory"); } \
    else         { asm volatile("s_waitcnt vmcnt(0)" ::: "memory"); } \
    barx(); \
    _Pragma("unroll") \
    for (int j = 0; j < 4; j++) pA[j] += BK; \
    pB1[0] += BK; pB1[1] += BK; pB3[0] += BK; pB3[1] += BK; \
}

    // NT = H/BK = 16 K-tiles, unrolled x2 for compile-time buffer index
    for (int tt = 0; tt < (H / BK) - 2; tt += 2) {
        S1_KT(0, false)
        S1_KT(1, false)
    }
    S1_KT(0, false)
    S1_KT(1, true)
#undef S1_DSA
#undef S1_MM
#undef S1_KT
#undef STA
#undef STB1
#undef STB3

    int rif = (lane >> 4) * 4;
#pragma unroll
    for (int m = 0; m < 8; m++) {
#pragma unroll
        for (int reg = 0; reg < 4; reg++) {
            int rowIdx = wr * 128 + m * 16 + rif + reg;
            int p = rbase + rowIdx;
            if (p < segEnd) {
                float g = pgateS[rowIdx];
#pragma unroll
                for (int n = 0; n < 2; n++) {
                    float a1 = acc1[m][n][reg], a3 = acc3[m][n][reg];
                    float sv = a1 / (1.f + __expf(-a1));
                    float hv = sv * a3 * g;
                    int ncol = nb + wc * 32 + n * 16 + (lane & 15);
                    h[(size_t)(p - chunkBase) * F + ncol] = f2bf(hv);
                }
            }
        }
    }
}

// ---------------- stage 2: y[p] = h[p] @ w2^T ----------------
// 256-row tile, BN = NREP*64, 8 waves, 2 barriers per K-tile (same invariants)
template<int NREP>
__global__ __launch_bounds__(512) void stage2_kernel(
    const u16* __restrict__ h, const u16* __restrict__ w2b,
    const int* __restrict__ offsets, const int* __restrict__ tileOff,
    u16* __restrict__ y, int cstart, int tpcThis) {
    constexpr int BN = NREP * 64;
    constexpr int BSTRIDE = BN * BK;       // elems per buf
    __shared__ u16 lA[2 * BM * BK];
    __shared__ u16 lB[2 * BSTRIDE];

    int tileL, nbIdx;
    decode_swz(blockIdx.x, tpcThis, H / BN, 4, tileL, nbIdx);
    int tile = cstart + tileL;
    if (tile >= tileOff[E_N]) return;
    int e = 0;
    while (e < E_N - 1 && tile >= tileOff[e + 1]) e++;
    int rbase = offsets[e] + (tile - tileOff[e]) * BM;
    int segEnd = offsets[e + 1];
    int e0 = 0;
    while (e0 < E_N - 1 && cstart >= tileOff[e0 + 1]) e0++;
    int chunkBase = offsets[e0] + (cstart - tileOff[e0]) * BM;

    int tid = threadIdx.x;
    int lane = tid & 63, wid = tid >> 6;
    int wr = wid >> 2, wc = wid & 3;
    int lrow = lane & 15, kgrp = lane >> 4;
    int lr = lane >> 3, csw = ((lane & 7) ^ lr) << 3;
    int nb = nbIdx * BN;
    const u16* w2p = w2b + (size_t)e * H * F + (size_t)nb * F;

    const u16* pA[4];
#pragma unroll
    for (int j = 0; j < 4; j++) {
        int rb = (j * 8 + wid) * 8;
        int p = rbase + rb + lr; if (p > segEnd - 1) p = segEnd - 1;
        pA[j] = h + (size_t)(p - chunkBase) * F + csw;
    }
    const u16* pB[NREP];
#pragma unroll
    for (int j = 0; j < NREP; j++) pB[j] = w2p + (size_t)((j * 8 + wid) * 8 + lr) * F + csw;

    int swe0 = (kgrp ^ (lrow & 7)) << 3;
    int swe1 = ((4 + kgrp) ^ (lrow & 7)) << 3;
    int eA0 = (wr * 128 + lrow) * BK + swe0;
    int eA1 = (wr * 128 + lrow) * BK + swe1;
    int eB0 = (wc * (NREP * 16) + lrow) * BK + swe0;
    int eB1 = (wc * (NREP * 16) + lrow) * BK + swe1;

#define STA2(CC, j) gload16(pA[j], &lA[(CC) * 16384 + ((j) * 8 + wid) * 8 * BK])
#define STB2(CC, j) gload16(pB[j], &lB[(CC) * BSTRIDE + ((j) * 8 + wid) * 8 * BK])

    float4v acc[8][NREP];
#pragma unroll
    for (int a = 0; a < 8; a++)
#pragma unroll
        for (int b = 0; b < NREP; b++) acc[a][b] = (float4v)(0.f);

    // prologue: A j1,j3 issued LAST (entry invariant = 2 outstanding)
#pragma unroll
    for (int j = 0; j < NREP; j++) STB2(0, j);
    STA2(0, 0); STA2(0, 2); STA2(0, 1); STA2(0, 3);
#pragma unroll
    for (int j = 0; j < 4; j++) pA[j] += BK;
#pragma unroll
    for (int j = 0; j < NREP; j++) pB[j] += BK;
    asm volatile("s_waitcnt vmcnt(2)" ::: "memory");
    barx();

#define S2_DSA(CC, p) \
    short8v aF[2][2]; \
    _Pragma("unroll") \
    for (int pm = 0; pm < 2; pm++) { \
        aF[pm][0] = *(const short8v*)&lA[eA0 + (CC) * 16384 + (2 * (p) + pm) * 1024]; \
        aF[pm][1] = *(const short8v*)&lA[eA1 + (CC) * 16384 + (2 * (p) + pm) * 1024]; \
    }
#define S2_MM(p) \
    __builtin_amdgcn_s_setprio(1); \
    _Pragma("unroll") \
    for (int pm = 0; pm < 2; pm++) \
    _Pragma("unroll") \
    for (int n = 0; n < NREP; n++) \
    _Pragma("unroll") \
    for (int kk = 0; kk < 2; kk++) \
        acc[2 * (p) + pm][n] = __builtin_amdgcn_mfma_f32_16x16x32_bf16(aF[pm][kk], bF[n][kk], acc[2 * (p) + pm][n], 0, 0, 0); \
    __builtin_amdgcn_s_setprio(0);

// 2 barriers per K-tile (mid vmcnt(6|4), end vmcnt(2))
#define S2_KT(CC, LAST) { \
    short8v bF[NREP][2]; \
    _Pragma("unroll") \
    for (int n = 0; n < NREP; n++) { \
        bF[n][0] = *(const short8v*)&lB[eB0 + (CC) * BSTRIDE + n * 1024]; \
        bF[n][1] = *(const short8v*)&lB[eB1 + (CC) * BSTRIDE + n * 1024]; \
    } \
    { S2_DSA(CC, 0) \
      if (!(LAST)) { STB2((CC) ^ 1, 0); if (NREP == 4) STB2((CC) ^ 1, 1); STA2((CC) ^ 1, 0); } \
      S2_MM(0) } \
    { S2_DSA(CC, 1) \
      if (!(LAST)) { if (NREP == 4) { STB2((CC) ^ 1, 2); STB2((CC) ^ 1, 3); } else STB2((CC) ^ 1, 1); \
                     STA2((CC) ^ 1, 2); } \
      S2_MM(1) } \
    if (!(LAST)) { \
        if (NREP == 4) { asm volatile("s_waitcnt vmcnt(6)" ::: "memory"); } \
        else           { asm volatile("s_waitcnt vmcnt(4)" ::: "memory"); } \
    } else { asm volatile("s_waitcnt vmcnt(0)" ::: "memory"); } \
    barx(); \
    { S2_DSA(CC, 2) \
      if (!(LAST)) { STA2((CC) ^ 1, 1); } \
      S2_MM(2) } \
    { S2_DSA(CC, 3) \
      if (!(LAST)) { STA2((CC) ^ 1, 3); } \
      S2_MM(3) } \
    if (!(LAST)) { asm volatile("s_waitcnt vmcnt(2)" ::: "memory"); } \
    else         { asm volatile("s_waitcnt vmcnt(0)" ::: "memory"); } \
    barx(); \
    _Pragma("unroll") \
    for (int j = 0; j < 4; j++) pA[j] += BK; \
    _Pragma("unroll") \
    for (int j = 0; j < NREP; j++) pB[j] += BK; \
}

    for (int tt = 0; tt < (F / BK) - 2; tt += 2) {
        S2_KT(0, false)
        S2_KT(1, false)
    }
    S2_KT(0, false)
    S2_KT(1, true)
#undef S2_DSA
#undef S2_MM
#undef S2_KT
#undef STA2
#undef STB2

    int rif = (lane >> 4) * 4;
#pragma unroll
    for (int m = 0; m < 8; m++) {
#pragma unroll
        for (int reg = 0; reg < 4; reg++) {
            int rowIdx = wr * 128 + m * 16 + rif + reg;
            int p = rbase + rowIdx;
            if (p < segEnd) {
#pragma unroll
                for (int n = 0; n < NREP; n++) {
                    int col = nb + wc * (BN / 4) + n * 16 + (lane & 15);
                    y[(size_t)p * H + col] = f2bf(acc[m][n][reg]);
                }
            }
        }
    }
}

// ---------------- combine: out[t] = y[slot0] + y[slot1] ----------------
__global__ __launch_bounds__(256) void combine_kernel(const u16* __restrict__ y,
                                                      const int* __restrict__ inv,
                                                      float* __restrict__ out) {
    int t = blockIdx.x, c = threadIdx.x;
    int s0 = inv[t * 2], s1 = inv[t * 2 + 1];
    ushort4 a = *(const ushort4*)(y + (size_t)s0 * H + c * 4);
    ushort4 b = *(const ushort4*)(y + (size_t)s1 * H + c * 4);
    float4 o;
    o.x = bf2f(a.x) + bf2f(b.x);
    o.y = bf2f(a.y) + bf2f(b.y);
    o.z = bf2f(a.z) + bf2f(b.z);
    o.w = bf2f(a.w) + bf2f(b.w);
    *(float4*)(out + (size_t)t * H + c * 4) = o;
}

extern "C" void kernel_launch(void* const* d_in, const int* in_sizes, int n_in,
                              void* d_out, int out_size, void* d_ws, size_t ws_size,
                              hipStream_t stream) {
    (void)n_in; (void)out_size;
    const float* x  = (const float*)d_in[0];
    const float* gw = (const float*)d_in[1];
    const float* w1 = (const float*)d_in[2];
    const float* w2 = (const float*)d_in[3];
    const float* w3 = (const float*)d_in[4];
    float* out = (float*)d_out;
    int T = in_sizes[0] / H;   // 16384
    int P = T * 2;

    char* ws = (char*)d_ws;
    size_t off = 0;
    auto alloc = [&](size_t b) { size_t c = off; off = (off + b + 255) & ~(size_t)255; return c; };
    size_t misc_o  = alloc(256);
    int* counts  = (int*)(ws + misc_o);
    int* offsets = (int*)(ws + misc_o + 64);
    int* cursors = (int*)(ws + misc_o + 128);
    int* tileOff = (int*)(ws + misc_o + 192);
    size_t topi_o  = alloc((size_t)T * 2 * 4);
    size_t topw_o  = alloc((size_t)T * 2 * 4);
    size_t ptok_o  = alloc((size_t)P * 4);
    size_t pgate_o = alloc((size_t)P * 4);
    size_t inv_o   = alloc((size_t)T * 2 * 4);
    size_t wb_o  = alloc((size_t)3 * NW * 2);    // w1b | w3b | w2b contiguous
    size_t xg_o  = alloc((size_t)T * H * 2);     // token-order bf16 x
    size_t y_o   = alloc((size_t)P * H * 2);     // bf16 per-slot output
    u16* w1b = (u16*)(ws + wb_o);
    u16* w3b = w1b + NW;
    u16* w2b = w1b + 2 * (size_t)NW;

    // h buffer sized from the ACTUAL remaining workspace (r12-proven: 62/62/12 split
    // keeps stage2<4> at 248 blocks for the big chunks; balancing regressed - r14)
    int maxTiles = P / BM + E_N;            // 136
    size_t perTile = (size_t)BM * F * 2;    // 1 MB
    size_t avail = (ws_size > off + 256) ? (ws_size - off - 256) : 0;
    int tpc = (int)(avail / perTile);
    if (tpc > maxTiles) tpc = maxTiles;
    if (tpc < 4) tpc = 4;
    size_t h_o = alloc((size_t)tpc * perTile);

    hipMemsetAsync(ws + misc_o, 0, 256, stream);

    cvt3_kernel<<<8192, 256, 0, stream>>>(w1, w3, w2, w1b);
    router_kernel<<<T / 4, 256, 0, stream>>>(x, gw, (int*)(ws + topi_o), (float*)(ws + topw_o),
                                             (u16*)(ws + xg_o), T);
    hist_kernel<<<32, 256, 0, stream>>>((int*)(ws + topi_o), counts, P);
    scan_kernel<<<1, 64, 0, stream>>>(counts, offsets, cursors, tileOff);
    scatter_kernel<<<(P + 1023) / 1024, 1024, 0, stream>>>(
        (int*)(ws + topi_o), (float*)(ws + topw_o), cursors,
        (int*)(ws + ptok_o), (float*)(ws + pgate_o), (int*)(ws + inv_o), P);

    for (int cstart = 0; cstart < maxTiles; cstart += tpc) {
        int tpcThis = maxTiles - cstart; if (tpcThis > tpc) tpcThis = tpc;
        stage1_kernel<<<tpcThis * (F / 128), 512, 0, stream>>>(
            (u16*)(ws + xg_o), w1b, w3b,
            (int*)(ws + ptok_o), (float*)(ws + pgate_o), offsets, tileOff,
            (u16*)(ws + h_o), cstart, tpcThis);
        if (tpcThis * 4 >= 240)
            stage2_kernel<4><<<tpcThis * (H / 256), 512, 0, stream>>>(
                (u16*)(ws + h_o), w2b, offsets, tileOff,
                (u16*)(ws + y_o), cstart, tpcThis);
        else
            stage2_kernel<2><<<tpcThis * (H / 128), 512, 0, stream>>>(
                (u16*)(ws + h_o), w2b, offsets, tileOff,
                (u16*)(ws + y_o), cstart, tpcThis);
    }
    combine_kernel<<<T, 256, 0, stream>>>((u16*)(ws + y_o), (int*)(ws + inv_o), out);
}

// Round 16
// 603.959 us; speedup vs baseline: 1.3002x; 1.0090x over previous
//
#include <hip/hip_runtime.h>
#include <cstdint>

#define H 1024
#define F 2048
#define E_N 8
#define BM 256
#define BK 64
#define NW (E_N * F * H)

typedef __attribute__((ext_vector_type(8))) short short8v;
typedef __attribute__((ext_vector_type(4))) float float4v;
typedef unsigned short u16;

__device__ __forceinline__ u16 f2bf(float f) {
    uint32_t u = __float_as_uint(f);
    u += 0x7FFFu + ((u >> 16) & 1u);   // round-to-nearest-even
    return (u16)(u >> 16);
}
__device__ __forceinline__ float bf2f(u16 b) {
    return __uint_as_float(((uint32_t)b) << 16);
}

__device__ __forceinline__ void gload16(const void* g, void* l) {
    __builtin_amdgcn_global_load_lds((const __attribute__((address_space(1))) uint32_t*)g,
                                     (__attribute__((address_space(3))) uint32_t*)l, 16, 0, 0);
}

// raw barrier (no vmcnt drain) with compiler memory fence
__device__ __forceinline__ void barx() {
    asm volatile("" ::: "memory");
    __builtin_amdgcn_s_barrier();
    asm volatile("" ::: "memory");
}

// bijective XCD chunk swizzle (m204) + tile-mid / gy-inner order
__device__ __forceinline__ void decode_swz(int bid, int nTiles, int ngy, int gyc,
                                           int& tile, int& gy) {
    int nblk = nTiles * ngy;
    int q = nblk >> 3, r = nblk & 7;
    int xcd = bid & 7, pos = bid >> 3;
    int cid = (xcd < r ? xcd * (q + 1) : r * (q + 1) + (xcd - r) * q) + pos;
    int per = nTiles * gyc;
    int chunk = cid / per, rem = cid - chunk * per;
    tile = rem / gyc;
    gy = chunk * gyc + (rem - (rem / gyc) * gyc);
}

// ---------------- fp32 -> bf16, 3 weight tensors in one launch ----------------
__global__ __launch_bounds__(256) void cvt3_kernel(const float* __restrict__ s0,
                                                   const float* __restrict__ s1,
                                                   const float* __restrict__ s2,
                                                   u16* __restrict__ dst) {
    int i = (blockIdx.x * 256 + threadIdx.x) * 4;
    int stride = gridDim.x * 256 * 4;
    for (; i < 3 * NW; i += stride) {
        int seg = i / NW;
        int off = i - seg * NW;
        const float* s = (seg == 0) ? s0 : ((seg == 1) ? s1 : s2);
        float4 v = *(const float4*)(s + off);
        ushort4 o;
        o.x = f2bf(v.x); o.y = f2bf(v.y); o.z = f2bf(v.z); o.w = f2bf(v.w);
        *(ushort4*)(dst + i) = o;
    }
}

// ---------------- router (no atomics) + fused x->bf16 ----------------
__global__ __launch_bounds__(256) void router_kernel(const float* __restrict__ x,
                                                     const float* __restrict__ gw,
                                                     int* __restrict__ topi,
                                                     float* __restrict__ topw,
                                                     u16* __restrict__ xg, int T) {
    int wave = threadIdx.x >> 6, lane = threadIdx.x & 63;
    int t = blockIdx.x * 4 + wave;
    if (t >= T) return;
    const float4* xr = (const float4*)(x + (size_t)t * H);
    float4 xv[4];
#pragma unroll
    for (int i = 0; i < 4; i++) xv[i] = xr[i * 64 + lane];
#pragma unroll
    for (int i = 0; i < 4; i++) {
        ushort4 o;
        o.x = f2bf(xv[i].x); o.y = f2bf(xv[i].y);
        o.z = f2bf(xv[i].z); o.w = f2bf(xv[i].w);
        *(ushort4*)(xg + (size_t)t * H + (i * 64 + lane) * 4) = o;
    }
    float acc[E_N];
#pragma unroll
    for (int e = 0; e < E_N; e++) {
        const float4* gr = (const float4*)(gw + e * H);
        float s = 0.f;
#pragma unroll
        for (int i = 0; i < 4; i++) {
            float4 g = gr[i * 64 + lane];
            s += xv[i].x * g.x + xv[i].y * g.y + xv[i].z * g.z + xv[i].w * g.w;
        }
        acc[e] = s;
    }
#pragma unroll
    for (int e = 0; e < E_N; e++) {
#pragma unroll
        for (int off = 32; off; off >>= 1) acc[e] += __shfl_xor(acc[e], off, 64);
    }
    if (lane == 0) {
        int i0 = 0;
#pragma unroll
        for (int e = 1; e < E_N; e++) if (acc[e] > acc[i0]) i0 = e;
        int i1 = -1;
#pragma unroll
        for (int e = 0; e < E_N; e++) {
            if (e == i0) continue;
            if (i1 < 0 || acc[e] > acc[i1]) i1 = e;
        }
        float e1 = __expf(acc[i1] - acc[i0]);
        float w0 = 1.f / (1.f + e1);
        float w1v = e1 / (1.f + e1);
        topi[t * 2] = i0; topi[t * 2 + 1] = i1;
        topw[t * 2] = w0; topw[t * 2 + 1] = w1v;
    }
}

// ---------------- histogram: 8 global atomics per block ----------------
__global__ __launch_bounds__(256) void hist_kernel(const int* __restrict__ topi,
                                                   int* __restrict__ counts, int n) {
    __shared__ int hc[E_N];
    if (threadIdx.x < E_N) hc[threadIdx.x] = 0;
    __syncthreads();
    for (int i = blockIdx.x * 256 + threadIdx.x; i < n; i += gridDim.x * 256)
        atomicAdd(&hc[topi[i]], 1);
    __syncthreads();
    if (threadIdx.x < E_N) atomicAdd(&counts[threadIdx.x], hc[threadIdx.x]);
}

// ---------------- tiny serial scan ----------------
__global__ void scan_kernel(const int* __restrict__ counts, int* __restrict__ offsets,
                            int* __restrict__ cursors, int* __restrict__ tileOff) {
    if (threadIdx.x == 0 && blockIdx.x == 0) {
        int o = 0, to = 0;
        for (int e = 0; e < E_N; e++) {
            offsets[e] = o; cursors[e] = o; tileOff[e] = to;
            o += counts[e];
            to += (counts[e] + BM - 1) / BM;
        }
        offsets[E_N] = o; tileOff[E_N] = to;
    }
}

// ---------------- scatter: block-local ranks, 8 global atomics per block ----------------
__global__ __launch_bounds__(1024) void scatter_kernel(const int* __restrict__ topi,
                                                       const float* __restrict__ topw,
                                                       int* __restrict__ cursors,
                                                       int* __restrict__ perm_tok,
                                                       float* __restrict__ perm_gate,
                                                       int* __restrict__ inv, int n) {
    __shared__ int hc[E_N];
    __shared__ int base[E_N];
    int tid = threadIdx.x;
    if (tid < E_N) hc[tid] = 0;
    __syncthreads();
    int i = blockIdx.x * 1024 + tid;
    int e = 0, lrank = 0;
    bool ok = (i < n);
    if (ok) {
        e = topi[i];
        lrank = atomicAdd(&hc[e], 1);
    }
    __syncthreads();
    if (tid < E_N) base[tid] = atomicAdd(&cursors[tid], hc[tid]);
    __syncthreads();
    if (ok) {
        int pos = base[e] + lrank;
        perm_tok[pos] = i >> 1;
        perm_gate[pos] = topw[i];
        inv[i] = pos;
    }
}

// ---------------- stage 1: h = gate * silu(xg@w1^T) * (xg@w3^T) ----------------
// 256-row tile, BN=128 (dual w1/w3), 8 waves, counted-vmcnt schedule with only
// TWO barriers per K-tile (mid: vmcnt(6) -> this tile's late A; end: vmcnt(2) ->
// next tile's early 6 + buffer-swap WAR). Phases free-flow between barriers.
__global__ __launch_bounds__(512) void stage1_kernel(
    const u16* __restrict__ xg, const u16* __restrict__ w1b, const u16* __restrict__ w3b,
    const int* __restrict__ perm_tok, const float* __restrict__ perm_gate,
    const int* __restrict__ offsets, const int* __restrict__ tileOff,
    u16* __restrict__ h, int cstart, int tpcThis) {
    __shared__ u16 lA[2 * BM * BK];      // 64 KB, buf stride 16384 elems
    __shared__ u16 lB1[2 * 128 * BK];    // 32 KB, buf stride 8192
    __shared__ u16 lB3[2 * 128 * BK];    // 32 KB
    __shared__ int ptokS[BM];
    __shared__ float pgateS[BM];

    int tileL, nbIdx;
    decode_swz(blockIdx.x, tpcThis, F / 128, 4, tileL, nbIdx);
    int tile = cstart + tileL;
    if (tile >= tileOff[E_N]) return;
    int e = 0;
    while (e < E_N - 1 && tile >= tileOff[e + 1]) e++;
    int rbase = offsets[e] + (tile - tileOff[e]) * BM;
    int segEnd = offsets[e + 1];
    int e0 = 0;
    while (e0 < E_N - 1 && cstart >= tileOff[e0 + 1]) e0++;
    int chunkBase = offsets[e0] + (cstart - tileOff[e0]) * BM;

    int tid = threadIdx.x;
    if (tid < BM) {
        int p = rbase + tid; if (p > segEnd - 1) p = segEnd - 1;
        ptokS[tid] = perm_tok[p];
        pgateS[tid] = perm_gate[p];
    }
    __syncthreads();

    int lane = tid & 63, wid = tid >> 6;
    int wr = wid >> 2, wc = wid & 3;
    int lrow = lane & 15, kgrp = lane >> 4;
    int lr = lane >> 3, csw = ((lane & 7) ^ lr) << 3;
    int nb = nbIdx * 128;
    const u16* w1p = w1b + (size_t)e * F * H + (size_t)nb * H;
    const u16* w3p = w3b + (size_t)e * F * H + (size_t)nb * H;

    // global stage pointers (swizzled-source; advance +BK per K-tile)
    const u16* pA[4];
#pragma unroll
    for (int j = 0; j < 4; j++) pA[j] = xg + (size_t)ptokS[(j * 8 + wid) * 8 + lr] * H + csw;
    const u16 *pB1[2], *pB3[2];
#pragma unroll
    for (int j = 0; j < 2; j++) {
        int rr = (j * 8 + wid) * 8 + lr;
        pB1[j] = w1p + (size_t)rr * H + csw;
        pB3[j] = w3p + (size_t)rr * H + csw;
    }

    // hoisted ds_read element bases (r&7 == lrow&7 for all fragment rows)
    int swe0 = (kgrp ^ (lrow & 7)) << 3;
    int swe1 = ((4 + kgrp) ^ (lrow & 7)) << 3;
    int eA0 = (wr * 128 + lrow) * BK + swe0;
    int eA1 = (wr * 128 + lrow) * BK + swe1;
    int eB0 = (wc * 32 + lrow) * BK + swe0;
    int eB1 = (wc * 32 + lrow) * BK + swe1;

#define STA(CC, j)  gload16(pA[j],  &lA[(CC) * 16384 + ((j) * 8 + wid) * 8 * BK])
#define STB1(CC, j) gload16(pB1[j], &lB1[(CC) * 8192 + ((j) * 8 + wid) * 8 * BK])
#define STB3(CC, j) gload16(pB3[j], &lB3[(CC) * 8192 + ((j) * 8 + wid) * 8 * BK])

    float4v acc1[8][2], acc3[8][2];
#pragma unroll
    for (int a = 0; a < 8; a++)
#pragma unroll
        for (int b = 0; b < 2; b++) { acc1[a][b] = (float4v)(0.f); acc3[a][b] = (float4v)(0.f); }

    // prologue: tile 0 into buf 0; A j1,j3 issued LAST (entry invariant = 2 outstanding)
    STB1(0, 0); STB1(0, 1);
    STB3(0, 0); STB3(0, 1);
    STA(0, 0); STA(0, 2); STA(0, 1); STA(0, 3);
#pragma unroll
    for (int j = 0; j < 4; j++) pA[j] += BK;
    pB1[0] += BK; pB1[1] += BK; pB3[0] += BK; pB3[1] += BK;
    asm volatile("s_waitcnt vmcnt(2)" ::: "memory");
    barx();

#define S1_DSA(CC, p) \
    short8v aF[2][2]; \
    _Pragma("unroll") \
    for (int pm = 0; pm < 2; pm++) { \
        aF[pm][0] = *(const short8v*)&lA[eA0 + (CC) * 16384 + (2 * (p) + pm) * 1024]; \
        aF[pm][1] = *(const short8v*)&lA[eA1 + (CC) * 16384 + (2 * (p) + pm) * 1024]; \
    }
#define S1_MM(p) \
    __builtin_amdgcn_s_setprio(1); \
    _Pragma("unroll") \
    for (int pm = 0; pm < 2; pm++) \
    _Pragma("unroll") \
    for (int n = 0; n < 2; n++) \
    _Pragma("unroll") \
    for (int kk = 0; kk < 2; kk++) { \
        acc1[2 * (p) + pm][n] = __builtin_amdgcn_mfma_f32_16x16x32_bf16(aF[pm][kk], b1F[n][kk], acc1[2 * (p) + pm][n], 0, 0, 0); \
        acc3[2 * (p) + pm][n] = __builtin_amdgcn_mfma_f32_16x16x32_bf16(aF[pm][kk], b3F[n][kk], acc3[2 * (p) + pm][n], 0, 0, 0); \
    } \
    __builtin_amdgcn_s_setprio(0);

// 2 barriers per K-tile: mid (after phases 0-1, vmcnt(6)) and end (vmcnt(2)).
#define S1_KT(CC, LAST) { \
    short8v b1F[2][2], b3F[2][2]; \
    _Pragma("unroll") \
    for (int n = 0; n < 2; n++) { \
        b1F[n][0] = *(const short8v*)&lB1[eB0 + (CC) * 8192 + n * 1024]; \
        b1F[n][1] = *(const short8v*)&lB1[eB1 + (CC) * 8192 + n * 1024]; \
        b3F[n][0] = *(const short8v*)&lB3[eB0 + (CC) * 8192 + n * 1024]; \
        b3F[n][1] = *(const short8v*)&lB3[eB1 + (CC) * 8192 + n * 1024]; \
    } \
    { S1_DSA(CC, 0) \
      if (!(LAST)) { STB1((CC) ^ 1, 0); STB1((CC) ^ 1, 1); STA((CC) ^ 1, 0); } \
      S1_MM(0) } \
    { S1_DSA(CC, 1) \
      if (!(LAST)) { STB3((CC) ^ 1, 0); STB3((CC) ^ 1, 1); STA((CC) ^ 1, 2); } \
      S1_MM(1) } \
    if (!(LAST)) { asm volatile("s_waitcnt vmcnt(6)" ::: "memory"); } \
    else         { asm volatile("s_waitcnt vmcnt(0)" ::: "memory"); } \
    barx(); \
    { S1_DSA(CC, 2) \
      if (!(LAST)) { STA((CC) ^ 1, 1); } \
      S1_MM(2) } \
    { S1_DSA(CC, 3) \
      if (!(LAST)) { STA((CC) ^ 1, 3); } \
      S1_MM(3) } \
    if (!(LAST)) { asm volatile("s_waitcnt vmcnt(2)" ::: "memory"); } \
    else         { asm volatile("s_waitcnt vmcnt(0)" ::: "memory"); } \
    barx(); \
    _Pragma("unroll") \
    for (int j = 0; j < 4; j++) pA[j] += BK; \
    pB1[0] += BK; pB1[1] += BK; pB3[0] += BK; pB3[1] += BK; \
}

    // NT = H/BK = 16 K-tiles, unrolled x2 for compile-time buffer index
    for (int tt = 0; tt < (H / BK) - 2; tt += 2) {
        S1_KT(0, false)
        S1_KT(1, false)
    }
    S1_KT(0, false)
    S1_KT(1, true)
#undef S1_DSA
#undef S1_MM
#undef S1_KT
#undef STA
#undef STB1
#undef STB3

    int rif = (lane >> 4) * 4;
#pragma unroll
    for (int m = 0; m < 8; m++) {
#pragma unroll
        for (int reg = 0; reg < 4; reg++) {
            int rowIdx = wr * 128 + m * 16 + rif + reg;
            int p = rbase + rowIdx;
            if (p < segEnd) {
                float g = pgateS[rowIdx];
#pragma unroll
                for (int n = 0; n < 2; n++) {
                    float a1 = acc1[m][n][reg], a3 = acc3[m][n][reg];
                    float sv = a1 / (1.f + __expf(-a1));
                    float hv = sv * a3 * g;
                    int ncol = nb + wc * 32 + n * 16 + (lane & 15);
                    h[(size_t)(p - chunkBase) * F + ncol] = f2bf(hv);
                }
            }
        }
    }
}

// ---------------- stage 2: y[p] = h[p] @ w2^T ----------------
// 256-row tile, BN = NREP*64, 8 waves, 2 barriers per K-tile (same invariants)
// mid-wait: NREP=4 -> vmcnt(6); NREP=2 -> vmcnt(4); NREP=1 -> vmcnt(3)
template<int NREP>
__global__ __launch_bounds__(512) void stage2_kernel(
    const u16* __restrict__ h, const u16* __restrict__ w2b,
    const int* __restrict__ offsets, const int* __restrict__ tileOff,
    u16* __restrict__ y, int cstart, int tpcThis) {
    constexpr int BN = NREP * 64;
    constexpr int BSTRIDE = BN * BK;       // elems per buf
    __shared__ u16 lA[2 * BM * BK];
    __shared__ u16 lB[2 * BSTRIDE];

    int tileL, nbIdx;
    decode_swz(blockIdx.x, tpcThis, H / BN, 4, tileL, nbIdx);
    int tile = cstart + tileL;
    if (tile >= tileOff[E_N]) return;
    int e = 0;
    while (e < E_N - 1 && tile >= tileOff[e + 1]) e++;
    int rbase = offsets[e] + (tile - tileOff[e]) * BM;
    int segEnd = offsets[e + 1];
    int e0 = 0;
    while (e0 < E_N - 1 && cstart >= tileOff[e0 + 1]) e0++;
    int chunkBase = offsets[e0] + (cstart - tileOff[e0]) * BM;

    int tid = threadIdx.x;
    int lane = tid & 63, wid = tid >> 6;
    int wr = wid >> 2, wc = wid & 3;
    int lrow = lane & 15, kgrp = lane >> 4;
    int lr = lane >> 3, csw = ((lane & 7) ^ lr) << 3;
    int nb = nbIdx * BN;
    const u16* w2p = w2b + (size_t)e * H * F + (size_t)nb * F;

    const u16* pA[4];
#pragma unroll
    for (int j = 0; j < 4; j++) {
        int rb = (j * 8 + wid) * 8;
        int p = rbase + rb + lr; if (p > segEnd - 1) p = segEnd - 1;
        pA[j] = h + (size_t)(p - chunkBase) * F + csw;
    }
    const u16* pB[NREP];
#pragma unroll
    for (int j = 0; j < NREP; j++) pB[j] = w2p + (size_t)((j * 8 + wid) * 8 + lr) * F + csw;

    int swe0 = (kgrp ^ (lrow & 7)) << 3;
    int swe1 = ((4 + kgrp) ^ (lrow & 7)) << 3;
    int eA0 = (wr * 128 + lrow) * BK + swe0;
    int eA1 = (wr * 128 + lrow) * BK + swe1;
    int eB0 = (wc * (NREP * 16) + lrow) * BK + swe0;
    int eB1 = (wc * (NREP * 16) + lrow) * BK + swe1;

#define STA2(CC, j) gload16(pA[j], &lA[(CC) * 16384 + ((j) * 8 + wid) * 8 * BK])
#define STB2(CC, j) gload16(pB[j], &lB[(CC) * BSTRIDE + ((j) * 8 + wid) * 8 * BK])

    float4v acc[8][NREP];
#pragma unroll
    for (int a = 0; a < 8; a++)
#pragma unroll
        for (int b = 0; b < NREP; b++) acc[a][b] = (float4v)(0.f);

    // prologue: A j1,j3 issued LAST (entry invariant = 2 outstanding)
#pragma unroll
    for (int j = 0; j < NREP; j++) STB2(0, j);
    STA2(0, 0); STA2(0, 2); STA2(0, 1); STA2(0, 3);
#pragma unroll
    for (int j = 0; j < 4; j++) pA[j] += BK;
#pragma unroll
    for (int j = 0; j < NREP; j++) pB[j] += BK;
    asm volatile("s_waitcnt vmcnt(2)" ::: "memory");
    barx();

#define S2_DSA(CC, p) \
    short8v aF[2][2]; \
    _Pragma("unroll") \
    for (int pm = 0; pm < 2; pm++) { \
        aF[pm][0] = *(const short8v*)&lA[eA0 + (CC) * 16384 + (2 * (p) + pm) * 1024]; \
        aF[pm][1] = *(const short8v*)&lA[eA1 + (CC) * 16384 + (2 * (p) + pm) * 1024]; \
    }
#define S2_MM(p) \
    __builtin_amdgcn_s_setprio(1); \
    _Pragma("unroll") \
    for (int pm = 0; pm < 2; pm++) \
    _Pragma("unroll") \
    for (int n = 0; n < NREP; n++) \
    _Pragma("unroll") \
    for (int kk = 0; kk < 2; kk++) \
        acc[2 * (p) + pm][n] = __builtin_amdgcn_mfma_f32_16x16x32_bf16(aF[pm][kk], bF[n][kk], acc[2 * (p) + pm][n], 0, 0, 0); \
    __builtin_amdgcn_s_setprio(0);

// 2 barriers per K-tile (mid vmcnt(6|4|3), end vmcnt(2))
#define S2_KT(CC, LAST) { \
    short8v bF[NREP][2]; \
    _Pragma("unroll") \
    for (int n = 0; n < NREP; n++) { \
        bF[n][0] = *(const short8v*)&lB[eB0 + (CC) * BSTRIDE + n * 1024]; \
        bF[n][1] = *(const short8v*)&lB[eB1 + (CC) * BSTRIDE + n * 1024]; \
    } \
    { S2_DSA(CC, 0) \
      if (!(LAST)) { STB2((CC) ^ 1, 0); if (NREP == 4) STB2((CC) ^ 1, 1); STA2((CC) ^ 1, 0); } \
      S2_MM(0) } \
    { S2_DSA(CC, 1) \
      if (!(LAST)) { if (NREP == 4) { STB2((CC) ^ 1, 2); STB2((CC) ^ 1, 3); } \
                     else if (NREP == 2) STB2((CC) ^ 1, 1); \
                     STA2((CC) ^ 1, 2); } \
      S2_MM(1) } \
    if (!(LAST)) { \
        if (NREP == 4)      { asm volatile("s_waitcnt vmcnt(6)" ::: "memory"); } \
        else if (NREP == 2) { asm volatile("s_waitcnt vmcnt(4)" ::: "memory"); } \
        else                { asm volatile("s_waitcnt vmcnt(3)" ::: "memory"); } \
    } else { asm volatile("s_waitcnt vmcnt(0)" ::: "memory"); } \
    barx(); \
    { S2_DSA(CC, 2) \
      if (!(LAST)) { STA2((CC) ^ 1, 1); } \
      S2_MM(2) } \
    { S2_DSA(CC, 3) \
      if (!(LAST)) { STA2((CC) ^ 1, 3); } \
      S2_MM(3) } \
    if (!(LAST)) { asm volatile("s_waitcnt vmcnt(2)" ::: "memory"); } \
    else         { asm volatile("s_waitcnt vmcnt(0)" ::: "memory"); } \
    barx(); \
    _Pragma("unroll") \
    for (int j = 0; j < 4; j++) pA[j] += BK; \
    _Pragma("unroll") \
    for (int j = 0; j < NREP; j++) pB[j] += BK; \
}

    for (int tt = 0; tt < (F / BK) - 2; tt += 2) {
        S2_KT(0, false)
        S2_KT(1, false)
    }
    S2_KT(0, false)
    S2_KT(1, true)
#undef S2_DSA
#undef S2_MM
#undef S2_KT
#undef STA2
#undef STB2

    int rif = (lane >> 4) * 4;
#pragma unroll
    for (int m = 0; m < 8; m++) {
#pragma unroll
        for (int reg = 0; reg < 4; reg++) {
            int rowIdx = wr * 128 + m * 16 + rif + reg;
            int p = rbase + rowIdx;
            if (p < segEnd) {
#pragma unroll
                for (int n = 0; n < NREP; n++) {
                    int col = nb + wc * (BN / 4) + n * 16 + (lane & 15);
                    y[(size_t)p * H + col] = f2bf(acc[m][n][reg]);
                }
            }
        }
    }
}

// ---------------- combine: out[t] = y[slot0] + y[slot1] ----------------
__global__ __launch_bounds__(256) void combine_kernel(const u16* __restrict__ y,
                                                      const int* __restrict__ inv,
                                                      float* __restrict__ out) {
    int t = blockIdx.x, c = threadIdx.x;
    int s0 = inv[t * 2], s1 = inv[t * 2 + 1];
    ushort4 a = *(const ushort4*)(y + (size_t)s0 * H + c * 4);
    ushort4 b = *(const ushort4*)(y + (size_t)s1 * H + c * 4);
    float4 o;
    o.x = bf2f(a.x) + bf2f(b.x);
    o.y = bf2f(a.y) + bf2f(b.y);
    o.z = bf2f(a.z) + bf2f(b.z);
    o.w = bf2f(a.w) + bf2f(b.w);
    *(float4*)(out + (size_t)t * H + c * 4) = o;
}

extern "C" void kernel_launch(void* const* d_in, const int* in_sizes, int n_in,
                              void* d_out, int out_size, void* d_ws, size_t ws_size,
                              hipStream_t stream) {
    (void)n_in; (void)out_size;
    const float* x  = (const float*)d_in[0];
    const float* gw = (const float*)d_in[1];
    const float* w1 = (const float*)d_in[2];
    const float* w2 = (const float*)d_in[3];
    const float* w3 = (const float*)d_in[4];
    float* out = (float*)d_out;
    int T = in_sizes[0] / H;   // 16384
    int P = T * 2;

    char* ws = (char*)d_ws;
    size_t off = 0;
    auto alloc = [&](size_t b) { size_t c = off; off = (off + b + 255) & ~(size_t)255; return c; };
    size_t misc_o  = alloc(256);
    int* counts  = (int*)(ws + misc_o);
    int* offsets = (int*)(ws + misc_o + 64);
    int* cursors = (int*)(ws + misc_o + 128);
    int* tileOff = (int*)(ws + misc_o + 192);
    size_t topi_o  = alloc((size_t)T * 2 * 4);
    size_t topw_o  = alloc((size_t)T * 2 * 4);
    size_t ptok_o  = alloc((size_t)P * 4);
    size_t pgate_o = alloc((size_t)P * 4);
    size_t inv_o   = alloc((size_t)T * 2 * 4);
    size_t wb_o  = alloc((size_t)3 * NW * 2);    // w1b | w3b | w2b contiguous
    size_t xg_o  = alloc((size_t)T * H * 2);     // token-order bf16 x
    size_t y_o   = alloc((size_t)P * H * 2);     // bf16 per-slot output
    u16* w1b = (u16*)(ws + wb_o);
    u16* w3b = w1b + NW;
    u16* w2b = w1b + 2 * (size_t)NW;

    // h buffer sized from the ACTUAL remaining workspace (62/62/12 split proven best;
    // balancing regressed via the stage2 NREP cliff - r14)
    int maxTiles = P / BM + E_N;            // 136
    size_t perTile = (size_t)BM * F * 2;    // 1 MB
    size_t avail = (ws_size > off + 256) ? (ws_size - off - 256) : 0;
    int tpc = (int)(avail / perTile);
    if (tpc > maxTiles) tpc = maxTiles;
    if (tpc < 4) tpc = 4;
    size_t h_o = alloc((size_t)tpc * perTile);

    hipMemsetAsync(ws + misc_o, 0, 256, stream);

    cvt3_kernel<<<8192, 256, 0, stream>>>(w1, w3, w2, w1b);
    router_kernel<<<T / 4, 256, 0, stream>>>(x, gw, (int*)(ws + topi_o), (float*)(ws + topw_o),
                                             (u16*)(ws + xg_o), T);
    hist_kernel<<<32, 256, 0, stream>>>((int*)(ws + topi_o), counts, P);
    scan_kernel<<<1, 64, 0, stream>>>(counts, offsets, cursors, tileOff);
    scatter_kernel<<<(P + 1023) / 1024, 1024, 0, stream>>>(
        (int*)(ws + topi_o), (float*)(ws + topw_o), cursors,
        (int*)(ws + ptok_o), (float*)(ws + pgate_o), (int*)(ws + inv_o), P);

    for (int cstart = 0; cstart < maxTiles; cstart += tpc) {
        int tpcThis = maxTiles - cstart; if (tpcThis > tpc) tpcThis = tpc;
        stage1_kernel<<<tpcThis * (F / 128), 512, 0, stream>>>(
            (u16*)(ws + xg_o), w1b, w3b,
            (int*)(ws + ptok_o), (float*)(ws + pgate_o), offsets, tileOff,
            (u16*)(ws + h_o), cstart, tpcThis);
        if (tpcThis * 4 >= 240)
            stage2_kernel<4><<<tpcThis * (H / 256), 512, 0, stream>>>(
                (u16*)(ws + h_o), w2b, offsets, tileOff,
                (u16*)(ws + y_o), cstart, tpcThis);
        else
            stage2_kernel<1><<<tpcThis * (H / 64), 512, 0, stream>>>(
                (u16*)(ws + h_o), w2b, offsets, tileOff,
                (u16*)(ws + y_o), cstart, tpcThis);
    }
    combine_kernel<<<T, 256, 0, stream>>>((u16*)(ws + y_o), (int*)(ws + inv_o), out);
}